// Round 8
// baseline (667.857 us; speedup 1.0000x reference)
//
#include <hip/hip_runtime.h>
#include <hip/hip_fp16.h>
#include <math.h>

// GCN 2-layer: N=100000 nodes, E=3200000 edges, 128 -> 16 -> 7
// R18: DELETE k_sort. Aggregation goes bucket-major over UNSORTED edges:
//      one block per bucket, LDS f32 accumulators (ds_add_f32, stride padded
//      17/9 to dodge the 16-bank stride trap), zero loop-carried deps in the
//      edge loop. dinv becomes a tiny bucket-major kernel (1 atomic/edge).
//      Removes: sort's 19MB read + 16MB write + LDS permute + rs/rc arrays.
//      append (R17 eval/edl format) and proj1 unchanged.
constexpr int NN = 100000;
constexpr int NE = 3200000;
constexpr int DF = 128;
constexpr int NH = 16;
constexpr int NC = 7;

constexpr int BN    = 256;                      // nodes per dst bucket (pow2)
constexpr int NB    = (NN + BN - 1) / BN;       // 391 buckets
constexpr int CAP   = 9216;                     // slots per bucket (mean 8184 + ~11 sigma)
constexpr int CHUNK = 4096;                     // edges per append block
constexpr int AB    = (NE + CHUNK - 1) / CHUNK; // 782
constexpr int EPT   = CHUNK / 1024;             // 4 edges per thread

constexpr float QS   = 32767.0f;
constexpr float QINV = 1.0f / 32767.0f;

typedef _Float16 half8 __attribute__((ext_vector_type(8)));
typedef float    f32x4 __attribute__((ext_vector_type(4)));

// ---------------- bucket append: LDS chunk-local counting sort, coalesced flush ----------------
__global__ void __launch_bounds__(1024)
k_append(const int* __restrict__ src,
         const int* __restrict__ dst,
         const float* __restrict__ w,
         int* __restrict__ gcur,
         unsigned* __restrict__ eval,
         unsigned char* __restrict__ edl) {
    __shared__ int hist[NB];                 // per-bucket count in this chunk
    __shared__ int cscan[512];               // inclusive scan of hist (padded)
    __shared__ int basev[NB];                // global base for this chunk's run
    __shared__ int wsum[8];                  // wave partials for scan
    __shared__ unsigned sval32[CHUNK];       // 16 KB: final compact value per slot
    __shared__ unsigned smeta[CHUNK];        // 16 KB: b (9b) | dl (8b) per slot
    int tid = threadIdx.x;
    for (int i = tid; i < NB; i += 1024) hist[i] = 0;
    __syncthreads();
    int e0 = blockIdx.x * CHUNK;
    unsigned sv[EPT], sm[EPT];
    int sbr[EPT];
#pragma unroll
    for (int k = 0; k < EPT; ++k) {
        int e = e0 + tid + k * 1024;
        sbr[k] = -1;
        if (e < NE) {
            int d = __builtin_nontemporal_load(dst + e);
            int b = d >> 8;
            int r = atomicAdd(&hist[b], 1);             // the only per-edge atomic
            unsigned q = (unsigned)(__builtin_nontemporal_load(w + e) * QS + 0.5f);
            sv[k] = (q << 17) |
                    (unsigned)__builtin_nontemporal_load(src + e);   // final compact value
            sm[k] = ((unsigned)b << 8) | (unsigned)(d & (BN - 1));   // b | dl
            sbr[k] = (b << 13) | r;                     // b<391 (9b), r<4096 (13b)
        }
    }
    __syncthreads();
    // inclusive scan of hist over 512 entries: 8 fully-active waves, shfl_up
    {
        int v = 0;
        if (tid < 512) {
            v = (tid < NB) ? hist[tid] : 0;
#pragma unroll
            for (int d = 1; d < 64; d <<= 1) {
                int u = __shfl_up(v, d, 64);
                if ((tid & 63) >= d) v += u;
            }
            if ((tid & 63) == 63) wsum[tid >> 6] = v;
        }
        __syncthreads();
        if (tid == 0) {
            int acc = 0;
#pragma unroll
            for (int i = 0; i < 8; ++i) { int t = wsum[i]; wsum[i] = acc; acc += t; }
        }
        __syncthreads();
        if (tid < 512) cscan[tid] = v + wsum[tid >> 6];
    }
    __syncthreads();
    if (tid < NB) {
        int c = hist[tid];
        basev[tid] = (c > 0) ? atomicAdd(&gcur[tid], c) : 0;
    }
    __syncthreads();
    // stage: LDS scatter into bucket-grouped order
#pragma unroll
    for (int k = 0; k < EPT; ++k) {
        if (sbr[k] >= 0) {
            int b = sbr[k] >> 13;
            int idx = (cscan[b] - hist[b]) + (sbr[k] & 0x1FFF);
            sval32[idx] = sv[k];
            smeta[idx]  = sm[k];
        }
    }
    __syncthreads();
    // flush: consecutive lanes write consecutive global slots within each bucket run
    int total = min(CHUNK, NE - e0);
    for (int i = tid; i < total; i += 1024) {
        unsigned mv = smeta[i];
        int b = (int)(mv >> 8);
        int st = cscan[b] - hist[b];
        int pos = basev[b] + (i - st);
        if (pos < CAP) {
            size_t g = (size_t)b * CAP + pos;
            eval[g] = sval32[i];
            edl[g]  = (unsigned char)(mv & 0xFF);
        }
    }
}

// ---------------- dinv per bucket: deg = 1 + sum(w), one LDS atomic/edge ----------------
__global__ void __launch_bounds__(1024)
k_dinv(const int* __restrict__ gcur,
       const unsigned* __restrict__ eval,
       const unsigned char* __restrict__ edl,
       float* __restrict__ dinv) {
    __shared__ float deg[BN];
    int b = blockIdx.x;
    int tid = threadIdx.x;
    int cnt = min(gcur[b], CAP);
    const unsigned* ev = eval + (size_t)b * CAP;
    const unsigned char* ed = edl + (size_t)b * CAP;
    if (tid < BN) deg[tid] = 1.0f;   // self-loop
    __syncthreads();
    for (int i = tid; i < cnt; i += 1024) {
        float w = (float)(ev[i] >> 17) * QINV;
        atomicAdd(&deg[ed[i]], w);
    }
    __syncthreads();
    if (tid < BN) {
        int n = b * BN + tid;
        if (n < NN) dinv[n] = rsqrtf(deg[tid]);
    }
}

// ---------------- h1' = fp16( dinv * (x @ W1) ) via MFMA, 1 wave per 16 nodes ----------------
__global__ void __launch_bounds__(256)
k_proj1(const float* __restrict__ x,
        const float* __restrict__ W1,
        const float* __restrict__ dinv,
        __half* __restrict__ h1p) {
    int wave = threadIdx.x >> 6;
    int lane = threadIdx.x & 63;
    int tile = blockIdx.x * 4 + wave;
    if (tile * 16 >= NN) return;
    int m    = lane & 15;   // A row (node within tile); also B/C column (feature)
    int quad = lane >> 4;
    // B fragments: B[k][n] with n = lane&15, k = kc*32 + quad*8 + j
    half8 bfrag[4];
#pragma unroll
    for (int kc = 0; kc < 4; ++kc)
#pragma unroll
        for (int j = 0; j < 8; ++j)
            bfrag[kc][j] = (_Float16)W1[(kc * 32 + quad * 8 + j) * NH + m];
    int base = tile * 16;
    const float* xr = x + (size_t)(base + m) * DF + quad * 8;
    f32x4 acc = {0.f, 0.f, 0.f, 0.f};
#pragma unroll
    for (int kc = 0; kc < 4; ++kc) {
        const float4* p = (const float4*)(xr + kc * 32);
        float4 u0 = p[0];
        float4 u1 = p[1];
        half8 afrag;
        afrag[0] = (_Float16)u0.x; afrag[1] = (_Float16)u0.y;
        afrag[2] = (_Float16)u0.z; afrag[3] = (_Float16)u0.w;
        afrag[4] = (_Float16)u1.x; afrag[5] = (_Float16)u1.y;
        afrag[6] = (_Float16)u1.z; afrag[7] = (_Float16)u1.w;
        acc = __builtin_amdgcn_mfma_f32_16x16x32_f16(afrag, bfrag[kc], acc, 0, 0, 0);
    }
    // epilogue: D[row=quad*4+reg][col=m] * dinv[row] -> h1p[(base+row)*16 + m]
    float4 d4 = *(const float4*)(dinv + base + quad * 4);
#pragma unroll
    for (int reg = 0; reg < 4; ++reg) {
        float dd = (reg == 0) ? d4.x : (reg == 1) ? d4.y : (reg == 2) ? d4.z : d4.w;
        int row = quad * 4 + reg;
        h1p[(size_t)(base + row) * 16 + m] = __float2half(acc[reg] * dd);
    }
}

// ---------------- layer-1 bucket-major aggregate + relu + proj2 fused ----------------
__global__ void __launch_bounds__(1024)
k_agg1B(const int* __restrict__ gcur,
        const unsigned* __restrict__ eval,
        const unsigned char* __restrict__ edl,
        const __half* __restrict__ h1p,
        const float* __restrict__ dinv,
        const float* __restrict__ b1,
        const float* __restrict__ W2,
        __half* __restrict__ h2p) {
    __shared__ float accf[BN * 17];   // stride 17: (dl*17+f)%32 spreads banks
    int b = blockIdx.x;
    int tid = threadIdx.x;
    int cnt = min(gcur[b], CAP);
    const unsigned* ev = eval + (size_t)b * CAP;
    const unsigned char* ed = edl + (size_t)b * CAP;
    // init: self term (h1p already includes dinv factor)
    for (int idx = tid; idx < BN * 16; idx += 1024) {
        int node = idx >> 4, f = idx & 15;
        int n = b * BN + node;
        accf[node * 17 + f] = (n < NN) ? __half2float(h1p[(size_t)n * 16 + f]) : 0.0f;
    }
    __syncthreads();
    // edge loop: NO loop-carried deps (fire-and-forget LDS atomics)
    for (int i = tid; i < cnt; i += 1024) {
        unsigned e = ev[i];
        int dl = (int)ed[i];
        float w = (float)(e >> 17) * QINV;
        const uint4* hp = (const uint4*)(h1p + (size_t)(e & 0x1FFFF) * 16);
        uint4 ua = hp[0];
        uint4 ub = hp[1];
        float* ac = &accf[dl * 17];
        float2 f0 = __half22float2(*(const __half2*)&ua.x);
        float2 f1 = __half22float2(*(const __half2*)&ua.y);
        float2 f2 = __half22float2(*(const __half2*)&ua.z);
        float2 f3 = __half22float2(*(const __half2*)&ua.w);
        float2 f4v = __half22float2(*(const __half2*)&ub.x);
        float2 f5 = __half22float2(*(const __half2*)&ub.y);
        float2 f6 = __half22float2(*(const __half2*)&ub.z);
        float2 f7 = __half22float2(*(const __half2*)&ub.w);
        atomicAdd(ac + 0,  w * f0.x);  atomicAdd(ac + 1,  w * f0.y);
        atomicAdd(ac + 2,  w * f1.x);  atomicAdd(ac + 3,  w * f1.y);
        atomicAdd(ac + 4,  w * f2.x);  atomicAdd(ac + 5,  w * f2.y);
        atomicAdd(ac + 6,  w * f3.x);  atomicAdd(ac + 7,  w * f3.y);
        atomicAdd(ac + 8,  w * f4v.x); atomicAdd(ac + 9,  w * f4v.y);
        atomicAdd(ac + 10, w * f5.x);  atomicAdd(ac + 11, w * f5.y);
        atomicAdd(ac + 12, w * f6.x);  atomicAdd(ac + 13, w * f6.y);
        atomicAdd(ac + 14, w * f7.x);  atomicAdd(ac + 15, w * f7.y);
    }
    __syncthreads();
    // epilogue: 4 threads/node (contiguous lanes): relu, @W2, *di -> h2p
    {
        int node = tid >> 2, f4 = tid & 3;
        int n = b * BN + node;
        if (n < NN) {
            const float* ac = &accf[node * 17 + 4 * f4];
            float di = dinv[n];
            int fb = 4 * f4;
            float hr0 = fmaxf(di * ac[0] + b1[fb + 0], 0.0f);
            float hr1 = fmaxf(di * ac[1] + b1[fb + 1], 0.0f);
            float hr2 = fmaxf(di * ac[2] + b1[fb + 2], 0.0f);
            float hr3 = fmaxf(di * ac[3] + b1[fb + 3], 0.0f);
            float p0, p1, p2, p3, p4, p5, p6;
            {
                const float* w0r = W2 + (fb + 0) * NC;
                const float* w1r = W2 + (fb + 1) * NC;
                const float* w2r = W2 + (fb + 2) * NC;
                const float* w3r = W2 + (fb + 3) * NC;
                p0 = hr0 * w0r[0] + hr1 * w1r[0] + hr2 * w2r[0] + hr3 * w3r[0];
                p1 = hr0 * w0r[1] + hr1 * w1r[1] + hr2 * w2r[1] + hr3 * w3r[1];
                p2 = hr0 * w0r[2] + hr1 * w1r[2] + hr2 * w2r[2] + hr3 * w3r[2];
                p3 = hr0 * w0r[3] + hr1 * w1r[3] + hr2 * w2r[3] + hr3 * w3r[3];
                p4 = hr0 * w0r[4] + hr1 * w1r[4] + hr2 * w2r[4] + hr3 * w3r[4];
                p5 = hr0 * w0r[5] + hr1 * w1r[5] + hr2 * w2r[5] + hr3 * w3r[5];
                p6 = hr0 * w0r[6] + hr1 * w1r[6] + hr2 * w2r[6] + hr3 * w3r[6];
            }
#pragma unroll
            for (int mask = 1; mask < 4; mask <<= 1) {
                p0 += __shfl_xor(p0, mask, 4);
                p1 += __shfl_xor(p1, mask, 4);
                p2 += __shfl_xor(p2, mask, 4);
                p3 += __shfl_xor(p3, mask, 4);
                p4 += __shfl_xor(p4, mask, 4);
                p5 += __shfl_xor(p5, mask, 4);
                p6 += __shfl_xor(p6, mask, 4);
            }
            float pa = (f4 == 0) ? p0 : (f4 == 1) ? p2 : (f4 == 2) ? p4 : p6;
            float pb = (f4 == 0) ? p1 : (f4 == 1) ? p3 : (f4 == 2) ? p5 : 0.0f;
            __half2 hv;
            hv.x = __float2half(di * pa);
            hv.y = __float2half(di * pb);
            ((__half2*)h2p)[n * 4 + f4] = hv;   // classes 2f4, 2f4+1 (pad 0)
        }
    }
}

// ---------------- layer-2 bucket-major aggregate + bias + log_softmax ----------------
__global__ void __launch_bounds__(1024)
k_agg2B(const int* __restrict__ gcur,
        const unsigned* __restrict__ eval,
        const unsigned char* __restrict__ edl,
        const __half* __restrict__ h2p,
        const float* __restrict__ dinv,
        const float* __restrict__ b2,
        float* __restrict__ out) {
    __shared__ float acc2[BN * 9];    // stride 9: (dl*9+f)%32 spreads banks
    int b = blockIdx.x;
    int tid = threadIdx.x;
    int cnt = min(gcur[b], CAP);
    const unsigned* ev = eval + (size_t)b * CAP;
    const unsigned char* ed = edl + (size_t)b * CAP;
    // init: self term (pad class 7 = 0 in h2p)
    for (int idx = tid; idx < BN * 8; idx += 1024) {
        int node = idx >> 3, f = idx & 7;
        int n = b * BN + node;
        acc2[node * 9 + f] = (n < NN) ? __half2float(h2p[(size_t)n * 8 + f]) : 0.0f;
    }
    __syncthreads();
    for (int i = tid; i < cnt; i += 1024) {
        unsigned e = ev[i];
        int dl = (int)ed[i];
        float w = (float)(e >> 17) * QINV;
        uint4 u = *(const uint4*)(h2p + (size_t)(e & 0x1FFFF) * 8);
        float* ac = &acc2[dl * 9];
        float2 f0 = __half22float2(*(const __half2*)&u.x);
        float2 f1 = __half22float2(*(const __half2*)&u.y);
        float2 f2 = __half22float2(*(const __half2*)&u.z);
        float2 f3 = __half22float2(*(const __half2*)&u.w);
        atomicAdd(ac + 0, w * f0.x);  atomicAdd(ac + 1, w * f0.y);
        atomicAdd(ac + 2, w * f1.x);  atomicAdd(ac + 3, w * f1.y);
        atomicAdd(ac + 4, w * f2.x);  atomicAdd(ac + 5, w * f2.y);
        atomicAdd(ac + 6, w * f3.x);  // class 7 is pad: skip the zero add
    }
    __syncthreads();
    // epilogue: 2 threads/node (contiguous lanes): bias + log_softmax
    if (tid < BN * 2) {
        int node = tid >> 1, c2 = tid & 1;
        int n = b * BN + node;
        if (n < NN) {
            const float* ac = &acc2[node * 9 + 4 * c2];
            float di = dinv[n];
            int cb = 4 * c2;
            float va0 = di * ac[0] + b2[cb + 0];
            float va1 = di * ac[1] + b2[cb + 1];
            float va2 = di * ac[2] + b2[cb + 2];
            float va3 = (c2 == 0) ? (di * ac[3] + b2[3]) : -1e30f;
            float m = fmaxf(fmaxf(va0, va1), fmaxf(va2, va3));
            m = fmaxf(m, __shfl_xor(m, 1, 2));
            float s = __expf(va0 - m) + __expf(va1 - m) + __expf(va2 - m)
                    + ((c2 == 0) ? __expf(va3 - m) : 0.0f);
            s += __shfl_xor(s, 1, 2);
            float lse = m + __logf(s);
            int base = n * NC + cb;
            out[base + 0] = va0 - lse;
            out[base + 1] = va1 - lse;
            out[base + 2] = va2 - lse;
            if (c2 == 0) out[base + 3] = va3 - lse;
        }
    }
}

extern "C" void kernel_launch(void* const* d_in, const int* in_sizes, int n_in,
                              void* d_out, int out_size, void* d_ws, size_t ws_size,
                              hipStream_t stream) {
    const float* x  = (const float*)d_in[0];
    const int*   ei = (const int*)d_in[1];
    const float* ew = (const float*)d_in[2];
    const float* W1 = (const float*)d_in[3];
    const float* b1 = (const float*)d_in[4];
    const float* W2 = (const float*)d_in[5];
    const float* b2 = (const float*)d_in[6];
    float* out = (float*)d_out;

    const int* srcp = ei;
    const int* dstp = ei + NE;

    // ws layout (4B units)
    float*  ws   = (float*)d_ws;
    float*  dinv = ws;                          // 100352
    __half* h1p  = (__half*)(ws + 100352);      // NN*16 halves = 800000 units
    __half* h2p  = (__half*)(ws + 900352);      // NN*8 halves = 400000 units
    int*    gcur = (int*)(ws + 1300352);        // 1024
    unsigned* eval = (unsigned*)(ws + 1301376); // NB*CAP u32 = 3,603,456 units
    unsigned char* edl = (unsigned char*)(ws + 4904832); // NB*CAP u8 = 900,864 units

    auto cdiv = [](long long a, long long b) { return (int)((a + b - 1) / b); };

    hipMemsetAsync(gcur, 0, NB * sizeof(int), stream);
    k_append<<<AB, 1024, 0, stream>>>(srcp, dstp, ew, gcur, eval, edl);
    k_dinv<<<NB, 1024, 0, stream>>>(gcur, eval, edl, dinv);
    k_proj1<<<cdiv(NN, 64), 256, 0, stream>>>(x, W1, dinv, h1p);  // 1563 blocks
    k_agg1B<<<NB, 1024, 0, stream>>>(gcur, eval, edl, h1p, dinv, b1, W2, h2p);
    k_agg2B<<<NB, 1024, 0, stream>>>(gcur, eval, edl, h2p, dinv, b2, out);
}

// Round 9
// 216.895 us; speedup vs baseline: 3.0792x; 3.0792x over previous
//
#include <hip/hip_runtime.h>
#include <hip/hip_fp16.h>
#include <math.h>

// GCN 2-layer: N=100000 nodes, E=3200000 edges, 128 -> 16 -> 7
// R19: revert R18's LDS-atomic aggregation (347us: LDS atomic throughput is
//      ~10x worse than modeled; VALUBusy 1.4% = pure serialization).
//      Base = R15 (best, 213.2us). New: fuse proj1 into k_sort's tail --
//      each sort block owns 256 nodes = 16 MFMA tiles = its 16 waves; dinv
//      is already in LDS. Removes the proj1 dispatch + dinv global re-read.
//      Risk: sort VGPR must stay <=64 for 2 blocks/CU (frags live after
//      stash dies; counter will adjudicate).
constexpr int NN = 100000;
constexpr int NE = 3200000;
constexpr int DF = 128;
constexpr int NH = 16;
constexpr int NC = 7;

constexpr int BN    = 256;                      // nodes per dst bucket (pow2)
constexpr int NB    = (NN + BN - 1) / BN;       // 391 buckets
constexpr int CAP   = 9216;                     // slots per bucket (mean 8184 + ~11 sigma)
constexpr int CHUNK = 4096;                     // edges per append block
constexpr int AB    = (NE + CHUNK - 1) / CHUNK; // 782
constexpr int EPT   = CHUNK / 1024;             // 4 edges per thread
constexpr int SPT   = (CAP + 1023) / 1024;      // 9 stash slots in sort

constexpr float QS   = 32767.0f;
constexpr float QINV = 1.0f / 32767.0f;

typedef _Float16 half8 __attribute__((ext_vector_type(8)));
typedef float    f32x4 __attribute__((ext_vector_type(4)));

// ---------------- bucket append: LDS chunk-local counting sort, coalesced flush ----------------
__global__ void __launch_bounds__(1024)
k_append(const int* __restrict__ src,
         const int* __restrict__ dst,
         const float* __restrict__ w,
         int* __restrict__ gcur,
         uint2* __restrict__ ebuf) {
    __shared__ int hist[NB];                 // per-bucket count in this chunk
    __shared__ int cscan[512];               // inclusive scan of hist (padded)
    __shared__ int basev[NB];                // global base for this chunk's run
    __shared__ int wsum[8];                  // wave partials for scan
    __shared__ uint2 staged[CHUNK];          // 32 KB: chunk edges grouped by bucket
    int tid = threadIdx.x;
    for (int i = tid; i < NB; i += 1024) hist[i] = 0;
    __syncthreads();
    int e0 = blockIdx.x * CHUNK;
    unsigned slo[EPT], sw[EPT];
    int sbr[EPT];
#pragma unroll
    for (int k = 0; k < EPT; ++k) {
        int e = e0 + tid + k * 1024;
        sbr[k] = -1;
        if (e < NE) {
            int d = __builtin_nontemporal_load(dst + e);
            int b = d >> 8;
            int r = atomicAdd(&hist[b], 1);             // the only per-edge atomic
            slo[k] = ((unsigned)(d & (BN - 1)) << 17) |
                     (unsigned)__builtin_nontemporal_load(src + e);
            unsigned q = (unsigned)(__builtin_nontemporal_load(w + e) * QS + 0.5f);
            sw[k]  = ((unsigned)b << 15) | q;           // b (9b) | q (15b)
            sbr[k] = (b << 13) | r;                     // b<391 (9b), r<4096 (13b)
        }
    }
    __syncthreads();
    // inclusive scan of hist over 512 entries: 8 fully-active waves, shfl_up
    {
        int v = 0;
        if (tid < 512) {
            v = (tid < NB) ? hist[tid] : 0;
#pragma unroll
            for (int d = 1; d < 64; d <<= 1) {
                int u = __shfl_up(v, d, 64);
                if ((tid & 63) >= d) v += u;
            }
            if ((tid & 63) == 63) wsum[tid >> 6] = v;
        }
        __syncthreads();
        if (tid == 0) {
            int acc = 0;
#pragma unroll
            for (int i = 0; i < 8; ++i) { int t = wsum[i]; wsum[i] = acc; acc += t; }
        }
        __syncthreads();
        if (tid < 512) cscan[tid] = v + wsum[tid >> 6];
    }
    __syncthreads();
    if (tid < NB) {
        int c = hist[tid];
        basev[tid] = (c > 0) ? atomicAdd(&gcur[tid], c) : 0;
    }
    __syncthreads();
    // stage: LDS scatter into bucket-grouped order
#pragma unroll
    for (int k = 0; k < EPT; ++k) {
        if (sbr[k] >= 0) {
            int b = sbr[k] >> 13;
            int idx = (cscan[b] - hist[b]) + (sbr[k] & 0x1FFF);
            uint2 v; v.x = slo[k]; v.y = sw[k];
            staged[idx] = v;
        }
    }
    __syncthreads();
    // flush: consecutive lanes write consecutive global slots within each bucket run
    int total = min(CHUNK, NE - e0);
    for (int i = tid; i < total; i += 1024) {
        uint2 sv = staged[i];
        int b = (int)(sv.y >> 15);
        int st = cscan[b] - hist[b];
        int pos = basev[b] + (i - st);
        if (pos < CAP) ebuf[(size_t)b * CAP + pos] = sv;
    }
}

// ---------------- intra-bucket counting sort + dinv + FUSED proj1 (MFMA) ----------------
__global__ void __launch_bounds__(1024)
k_sort(const int* __restrict__ gcur,
       uint2* __restrict__ ebuf,
       int* __restrict__ rs,
       int* __restrict__ rc,
       float* __restrict__ dinv,
       const float* __restrict__ x,
       const float* __restrict__ W1,
       __half* __restrict__ h1p) {
    __shared__ int cursor[BN];    // counts after loop1
    __shared__ int scanS[BN];
    __shared__ int startEx[BN];
    __shared__ int wsum[4];
    __shared__ float ddv[BN];     // dinv for this bucket's 256 nodes
    __shared__ unsigned sorted[CAP];  // 36 KB
    int b = blockIdx.x;
    int tid = threadIdx.x;
    int cnt = min(gcur[b], CAP);
    const uint2* eb = ebuf + (size_t)b * CAP;
    if (tid < BN) cursor[tid] = 0;
    __syncthreads();
    unsigned sval[SPT];
    int sdr[SPT];
#pragma unroll
    for (int k = 0; k < SPT; ++k) {
        int i = tid + k * 1024;
        sdr[k] = -1;
        if (i < cnt) {
            uint2 v = eb[i];
            int dl = (v.x >> 17) & (BN - 1);
            int r = atomicAdd(&cursor[dl], 1);          // the only per-edge atomic
            sval[k] = (v.x & 0x1FFFF) | ((v.y & 0x7FFFu) << 17);  // src | q
            sdr[k] = (dl << 14) | r;                    // dl (8b), r<9216 (14b)
        }
    }
    __syncthreads();
    // inclusive scan of cursor over 256 entries: 4 fully-active waves, shfl_up
    {
        int v = 0;
        if (tid < BN) {
            v = cursor[tid];
#pragma unroll
            for (int d = 1; d < 64; d <<= 1) {
                int u = __shfl_up(v, d, 64);
                if ((tid & 63) >= d) v += u;
            }
            if ((tid & 63) == 63) wsum[tid >> 6] = v;
        }
        __syncthreads();
        if (tid == 0) {
            int acc = 0;
#pragma unroll
            for (int i = 0; i < 4; ++i) { int t = wsum[i]; wsum[i] = acc; acc += t; }
        }
        __syncthreads();
        if (tid < BN) scanS[tid] = v + wsum[tid >> 6];
    }
    __syncthreads();
    if (tid < BN) {
        int ex = scanS[tid] - cursor[tid];
        startEx[tid] = ex;
        int n = b * BN + tid;
        if (n < NN) { rs[n] = b * CAP * 2 + ex; rc[n] = cursor[tid]; }  // u32 index
    }
    __syncthreads();
#pragma unroll
    for (int k = 0; k < SPT; ++k) {
        if (sdr[k] >= 0)
            sorted[startEx[sdr[k] >> 14] + (sdr[k] & 0x3FFF)] = sval[k];
    }
    __syncthreads();
    unsigned* eb32 = (unsigned*)ebuf + (size_t)b * CAP * 2;
    for (int i = tid; i < cnt; i += 1024) eb32[i] = sorted[i];
    // dinv: 4 threads per node, shfl-reduce -> LDS ddv + global dinv
    {
        int node = tid >> 2, part = tid & 3;
        float s = (part == 0) ? 1.0f : 0.0f;  // self-loop
        int s0 = startEx[node], c = cursor[node];
        for (int i = part; i < c; i += 4) s += (float)(sorted[s0 + i] >> 17) * QINV;
        s += __shfl_xor(s, 1, 4);
        s += __shfl_xor(s, 2, 4);
        if (part == 0) {
            float r = rsqrtf(s);
            ddv[node] = r;
            int n = b * BN + node;
            if (n < NN) dinv[n] = r;
        }
    }
    __syncthreads();
    // FUSED proj1: wave wv handles the 16-node tile at base = b*256 + wv*16.
    // h1p[n][m] = ddv[n] * sum_k x[n][k] * W1[k][m]   (fp16 out)
    {
        int wv = tid >> 6;      // 0..15
        int lane = tid & 63;
        int m = lane & 15;      // A row (node within tile); also B/C column
        int quad = lane >> 4;
        half8 bfrag[4];
#pragma unroll
        for (int kc = 0; kc < 4; ++kc)
#pragma unroll
            for (int j = 0; j < 8; ++j)
                bfrag[kc][j] = (_Float16)W1[(kc * 32 + quad * 8 + j) * NH + m];
        int base = b * BN + wv * 16;
        int xrow = min(base + m, NN - 1);   // clamp: last bucket overhangs NN
        const float* xr = x + (size_t)xrow * DF + quad * 8;
        f32x4 acc = {0.f, 0.f, 0.f, 0.f};
#pragma unroll
        for (int kc = 0; kc < 4; ++kc) {
            const float4* p = (const float4*)(xr + kc * 32);
            float4 u0 = p[0];
            float4 u1 = p[1];
            half8 afrag;
            afrag[0] = (_Float16)u0.x; afrag[1] = (_Float16)u0.y;
            afrag[2] = (_Float16)u0.z; afrag[3] = (_Float16)u0.w;
            afrag[4] = (_Float16)u1.x; afrag[5] = (_Float16)u1.y;
            afrag[6] = (_Float16)u1.z; afrag[7] = (_Float16)u1.w;
            acc = __builtin_amdgcn_mfma_f32_16x16x32_f16(afrag, bfrag[kc], acc, 0, 0, 0);
        }
        // D[row=quad*4+reg][col=m] * ddv[row] -> h1p[(base+row)*16 + m]
#pragma unroll
        for (int reg = 0; reg < 4; ++reg) {
            int row = quad * 4 + reg;
            int n = base + row;
            if (n < NN)
                h1p[(size_t)n * 16 + m] = __float2half(acc[reg] * ddv[wv * 16 + row]);
        }
    }
}

// ---------------- layer-1 aggregate + relu + proj2 fused (4 lanes/node, unroll-8 named) ----------------
__global__ void __launch_bounds__(256)
k_agg1p(const int* __restrict__ rs,
        const int* __restrict__ rc,
        const unsigned* __restrict__ cbuf,
        const __half* __restrict__ h1p,
        const float* __restrict__ dinv,
        const float* __restrict__ b1,
        const float* __restrict__ W2,
        __half* __restrict__ h2p) {
    const uint2* hp4 = (const uint2*)h1p;  // [NN*4], 4 halves each
    int t = blockIdx.x * 256 + threadIdx.x;
    int n = t >> 2;
    int f4 = t & 3;   // features 4*f4 .. 4*f4+3
    if (n >= NN) return;
    float a0, a1, a2, a3;
    {
        uint2 u = hp4[n * 4 + f4];  // self term
        float2 lo = __half22float2(*(const __half2*)&u.x);
        float2 hi = __half22float2(*(const __half2*)&u.y);
        a0 = lo.x; a1 = lo.y; a2 = hi.x; a3 = hi.y;
    }
    int s0 = rs[n], c = rc[n];
    int i = 0;
    for (; i + 7 < c; i += 8) {
        unsigned e0 = cbuf[s0 + i];
        unsigned e1 = cbuf[s0 + i + 1];
        unsigned e2 = cbuf[s0 + i + 2];
        unsigned e3 = cbuf[s0 + i + 3];
        unsigned e4 = cbuf[s0 + i + 4];
        unsigned e5 = cbuf[s0 + i + 5];
        unsigned e6 = cbuf[s0 + i + 6];
        unsigned e7 = cbuf[s0 + i + 7];
        uint2 u0 = hp4[(e0 & 0x1FFFF) * 4 + f4];
        uint2 u1 = hp4[(e1 & 0x1FFFF) * 4 + f4];
        uint2 u2 = hp4[(e2 & 0x1FFFF) * 4 + f4];
        uint2 u3 = hp4[(e3 & 0x1FFFF) * 4 + f4];
        uint2 u4 = hp4[(e4 & 0x1FFFF) * 4 + f4];
        uint2 u5 = hp4[(e5 & 0x1FFFF) * 4 + f4];
        uint2 u6 = hp4[(e6 & 0x1FFFF) * 4 + f4];
        uint2 u7 = hp4[(e7 & 0x1FFFF) * 4 + f4];
        float w0 = (float)(e0 >> 17) * QINV;
        float w1 = (float)(e1 >> 17) * QINV;
        float w2 = (float)(e2 >> 17) * QINV;
        float w3 = (float)(e3 >> 17) * QINV;
        float w4 = (float)(e4 >> 17) * QINV;
        float w5 = (float)(e5 >> 17) * QINV;
        float w6 = (float)(e6 >> 17) * QINV;
        float w7 = (float)(e7 >> 17) * QINV;
        float2 l0 = __half22float2(*(const __half2*)&u0.x);
        float2 h0 = __half22float2(*(const __half2*)&u0.y);
        float2 l1 = __half22float2(*(const __half2*)&u1.x);
        float2 h1v = __half22float2(*(const __half2*)&u1.y);
        float2 l2 = __half22float2(*(const __half2*)&u2.x);
        float2 h2v = __half22float2(*(const __half2*)&u2.y);
        float2 l3 = __half22float2(*(const __half2*)&u3.x);
        float2 h3v = __half22float2(*(const __half2*)&u3.y);
        float2 l4 = __half22float2(*(const __half2*)&u4.x);
        float2 h4v = __half22float2(*(const __half2*)&u4.y);
        float2 l5 = __half22float2(*(const __half2*)&u5.x);
        float2 h5v = __half22float2(*(const __half2*)&u5.y);
        float2 l6 = __half22float2(*(const __half2*)&u6.x);
        float2 h6v = __half22float2(*(const __half2*)&u6.y);
        float2 l7 = __half22float2(*(const __half2*)&u7.x);
        float2 h7v = __half22float2(*(const __half2*)&u7.y);
        a0 += w0 * l0.x + w1 * l1.x + w2 * l2.x + w3 * l3.x
            + w4 * l4.x + w5 * l5.x + w6 * l6.x + w7 * l7.x;
        a1 += w0 * l0.y + w1 * l1.y + w2 * l2.y + w3 * l3.y
            + w4 * l4.y + w5 * l5.y + w6 * l6.y + w7 * l7.y;
        a2 += w0 * h0.x + w1 * h1v.x + w2 * h2v.x + w3 * h3v.x
            + w4 * h4v.x + w5 * h5v.x + w6 * h6v.x + w7 * h7v.x;
        a3 += w0 * h0.y + w1 * h1v.y + w2 * h2v.y + w3 * h3v.y
            + w4 * h4v.y + w5 * h5v.y + w6 * h6v.y + w7 * h7v.y;
    }
    for (; i + 3 < c; i += 4) {
        unsigned e0 = cbuf[s0 + i];
        unsigned e1 = cbuf[s0 + i + 1];
        unsigned e2 = cbuf[s0 + i + 2];
        unsigned e3 = cbuf[s0 + i + 3];
        uint2 u0 = hp4[(e0 & 0x1FFFF) * 4 + f4];
        uint2 u1 = hp4[(e1 & 0x1FFFF) * 4 + f4];
        uint2 u2 = hp4[(e2 & 0x1FFFF) * 4 + f4];
        uint2 u3 = hp4[(e3 & 0x1FFFF) * 4 + f4];
        float w0 = (float)(e0 >> 17) * QINV;
        float w1 = (float)(e1 >> 17) * QINV;
        float w2 = (float)(e2 >> 17) * QINV;
        float w3 = (float)(e3 >> 17) * QINV;
        float2 l0 = __half22float2(*(const __half2*)&u0.x);
        float2 h0 = __half22float2(*(const __half2*)&u0.y);
        float2 l1 = __half22float2(*(const __half2*)&u1.x);
        float2 h1v = __half22float2(*(const __half2*)&u1.y);
        float2 l2 = __half22float2(*(const __half2*)&u2.x);
        float2 h2v = __half22float2(*(const __half2*)&u2.y);
        float2 l3 = __half22float2(*(const __half2*)&u3.x);
        float2 h3v = __half22float2(*(const __half2*)&u3.y);
        a0 += w0 * l0.x + w1 * l1.x + w2 * l2.x + w3 * l3.x;
        a1 += w0 * l0.y + w1 * l1.y + w2 * l2.y + w3 * l3.y;
        a2 += w0 * h0.x + w1 * h1v.x + w2 * h2v.x + w3 * h3v.x;
        a3 += w0 * h0.y + w1 * h1v.y + w2 * h2v.y + w3 * h3v.y;
    }
    for (; i < c; ++i) {
        unsigned e0 = cbuf[s0 + i];
        uint2 u0 = hp4[(e0 & 0x1FFFF) * 4 + f4];
        float w0 = (float)(e0 >> 17) * QINV;
        float2 l0 = __half22float2(*(const __half2*)&u0.x);
        float2 h0 = __half22float2(*(const __half2*)&u0.y);
        a0 += w0 * l0.x;
        a1 += w0 * l0.y;
        a2 += w0 * h0.x;
        a3 += w0 * h0.y;
    }
    // fused epilogue: out1 = di*a + b1, relu, @W2, *di -> h2p (fp16)
    float di = dinv[n];
    int fb = 4 * f4;
    float hr0 = fmaxf(di * a0 + b1[fb + 0], 0.0f);
    float hr1 = fmaxf(di * a1 + b1[fb + 1], 0.0f);
    float hr2 = fmaxf(di * a2 + b1[fb + 2], 0.0f);
    float hr3 = fmaxf(di * a3 + b1[fb + 3], 0.0f);
    float p0, p1, p2, p3, p4, p5, p6;
    {
        const float* w0r = W2 + (fb + 0) * NC;
        const float* w1r = W2 + (fb + 1) * NC;
        const float* w2r = W2 + (fb + 2) * NC;
        const float* w3r = W2 + (fb + 3) * NC;
        p0 = hr0 * w0r[0] + hr1 * w1r[0] + hr2 * w2r[0] + hr3 * w3r[0];
        p1 = hr0 * w0r[1] + hr1 * w1r[1] + hr2 * w2r[1] + hr3 * w3r[1];
        p2 = hr0 * w0r[2] + hr1 * w1r[2] + hr2 * w2r[2] + hr3 * w3r[2];
        p3 = hr0 * w0r[3] + hr1 * w1r[3] + hr2 * w2r[3] + hr3 * w3r[3];
        p4 = hr0 * w0r[4] + hr1 * w1r[4] + hr2 * w2r[4] + hr3 * w3r[4];
        p5 = hr0 * w0r[5] + hr1 * w1r[5] + hr2 * w2r[5] + hr3 * w3r[5];
        p6 = hr0 * w0r[6] + hr1 * w1r[6] + hr2 * w2r[6] + hr3 * w3r[6];
    }
#pragma unroll
    for (int mask = 1; mask < 4; mask <<= 1) {
        p0 += __shfl_xor(p0, mask, 4);
        p1 += __shfl_xor(p1, mask, 4);
        p2 += __shfl_xor(p2, mask, 4);
        p3 += __shfl_xor(p3, mask, 4);
        p4 += __shfl_xor(p4, mask, 4);
        p5 += __shfl_xor(p5, mask, 4);
        p6 += __shfl_xor(p6, mask, 4);
    }
    // lane f4 writes classes 2*f4, 2*f4+1 (lane 3 second = pad 0)
    float pa = (f4 == 0) ? p0 : (f4 == 1) ? p2 : (f4 == 2) ? p4 : p6;
    float pb = (f4 == 0) ? p1 : (f4 == 1) ? p3 : (f4 == 2) ? p5 : 0.0f;
    __half2 hv;
    hv.x = __float2half(di * pa);
    hv.y = __float2half(di * pb);
    ((__half2*)h2p)[n * 4 + f4] = hv;
}

// ---------------- layer-2 aggregate (2 lanes/node, unroll-8 named) + bias + log_softmax ----------------
__global__ void __launch_bounds__(256)
k_agg2_lsm(const int* __restrict__ rs,
           const int* __restrict__ rc,
           const unsigned* __restrict__ cbuf,
           const __half* __restrict__ h2p,
           const float* __restrict__ dinv,
           const float* __restrict__ b2,
           float* __restrict__ out) {
    const uint2* hp2 = (const uint2*)h2p;  // [NN*2], 4 halves each
    int t = blockIdx.x * 256 + threadIdx.x;
    int n = t >> 1;
    int c2 = t & 1;   // classes 4*c2 .. 4*c2+3 (lane1 last = pad)
    if (n >= NN) return;
    float a0, a1, a2, a3;
    {
        uint2 u = hp2[n * 2 + c2];  // self term (pad slot = 0)
        float2 lo = __half22float2(*(const __half2*)&u.x);
        float2 hi = __half22float2(*(const __half2*)&u.y);
        a0 = lo.x; a1 = lo.y; a2 = hi.x; a3 = hi.y;
    }
    int s0 = rs[n], c = rc[n];
    int i = 0;
    for (; i + 7 < c; i += 8) {
        unsigned e0 = cbuf[s0 + i];
        unsigned e1 = cbuf[s0 + i + 1];
        unsigned e2 = cbuf[s0 + i + 2];
        unsigned e3 = cbuf[s0 + i + 3];
        unsigned e4 = cbuf[s0 + i + 4];
        unsigned e5 = cbuf[s0 + i + 5];
        unsigned e6 = cbuf[s0 + i + 6];
        unsigned e7 = cbuf[s0 + i + 7];
        uint2 u0 = hp2[(e0 & 0x1FFFF) * 2 + c2];
        uint2 u1 = hp2[(e1 & 0x1FFFF) * 2 + c2];
        uint2 u2 = hp2[(e2 & 0x1FFFF) * 2 + c2];
        uint2 u3 = hp2[(e3 & 0x1FFFF) * 2 + c2];
        uint2 u4 = hp2[(e4 & 0x1FFFF) * 2 + c2];
        uint2 u5 = hp2[(e5 & 0x1FFFF) * 2 + c2];
        uint2 u6 = hp2[(e6 & 0x1FFFF) * 2 + c2];
        uint2 u7 = hp2[(e7 & 0x1FFFF) * 2 + c2];
        float w0 = (float)(e0 >> 17) * QINV;
        float w1 = (float)(e1 >> 17) * QINV;
        float w2 = (float)(e2 >> 17) * QINV;
        float w3 = (float)(e3 >> 17) * QINV;
        float w4 = (float)(e4 >> 17) * QINV;
        float w5 = (float)(e5 >> 17) * QINV;
        float w6 = (float)(e6 >> 17) * QINV;
        float w7 = (float)(e7 >> 17) * QINV;
        float2 l0 = __half22float2(*(const __half2*)&u0.x);
        float2 h0 = __half22float2(*(const __half2*)&u0.y);
        float2 l1 = __half22float2(*(const __half2*)&u1.x);
        float2 h1v = __half22float2(*(const __half2*)&u1.y);
        float2 l2 = __half22float2(*(const __half2*)&u2.x);
        float2 h2v = __half22float2(*(const __half2*)&u2.y);
        float2 l3 = __half22float2(*(const __half2*)&u3.x);
        float2 h3v = __half22float2(*(const __half2*)&u3.y);
        float2 l4 = __half22float2(*(const __half2*)&u4.x);
        float2 h4v = __half22float2(*(const __half2*)&u4.y);
        float2 l5 = __half22float2(*(const __half2*)&u5.x);
        float2 h5v = __half22float2(*(const __half2*)&u5.y);
        float2 l6 = __half22float2(*(const __half2*)&u6.x);
        float2 h6v = __half22float2(*(const __half2*)&u6.y);
        float2 l7 = __half22float2(*(const __half2*)&u7.x);
        float2 h7v = __half22float2(*(const __half2*)&u7.y);
        a0 += w0 * l0.x + w1 * l1.x + w2 * l2.x + w3 * l3.x
            + w4 * l4.x + w5 * l5.x + w6 * l6.x + w7 * l7.x;
        a1 += w0 * l0.y + w1 * l1.y + w2 * l2.y + w3 * l3.y
            + w4 * l4.y + w5 * l5.y + w6 * l6.y + w7 * l7.y;
        a2 += w0 * h0.x + w1 * h1v.x + w2 * h2v.x + w3 * h3v.x
            + w4 * h4v.x + w5 * h5v.x + w6 * h6v.x + w7 * h7v.x;
        a3 += w0 * h0.y + w1 * h1v.y + w2 * h2v.y + w3 * h3v.y
            + w4 * h4v.y + w5 * h5v.y + w6 * h6v.y + w7 * h7v.y;
    }
    for (; i + 3 < c; i += 4) {
        unsigned e0 = cbuf[s0 + i];
        unsigned e1 = cbuf[s0 + i + 1];
        unsigned e2 = cbuf[s0 + i + 2];
        unsigned e3 = cbuf[s0 + i + 3];
        uint2 u0 = hp2[(e0 & 0x1FFFF) * 2 + c2];
        uint2 u1 = hp2[(e1 & 0x1FFFF) * 2 + c2];
        uint2 u2 = hp2[(e2 & 0x1FFFF) * 2 + c2];
        uint2 u3 = hp2[(e3 & 0x1FFFF) * 2 + c2];
        float w0 = (float)(e0 >> 17) * QINV;
        float w1 = (float)(e1 >> 17) * QINV;
        float w2 = (float)(e2 >> 17) * QINV;
        float w3 = (float)(e3 >> 17) * QINV;
        float2 l0 = __half22float2(*(const __half2*)&u0.x);
        float2 h0 = __half22float2(*(const __half2*)&u0.y);
        float2 l1 = __half22float2(*(const __half2*)&u1.x);
        float2 h1v = __half22float2(*(const __half2*)&u1.y);
        float2 l2 = __half22float2(*(const __half2*)&u2.x);
        float2 h2v = __half22float2(*(const __half2*)&u2.y);
        float2 l3 = __half22float2(*(const __half2*)&u3.x);
        float2 h3v = __half22float2(*(const __half2*)&u3.y);
        a0 += w0 * l0.x + w1 * l1.x + w2 * l2.x + w3 * l3.x;
        a1 += w0 * l0.y + w1 * l1.y + w2 * l2.y + w3 * l3.y;
        a2 += w0 * h0.x + w1 * h1v.x + w2 * h2v.x + w3 * h3v.x;
        a3 += w0 * h0.y + w1 * h1v.y + w2 * h2v.y + w3 * h3v.y;
    }
    for (; i < c; ++i) {
        unsigned e0 = cbuf[s0 + i];
        uint2 u0 = hp2[(e0 & 0x1FFFF) * 2 + c2];
        float w0 = (float)(e0 >> 17) * QINV;
        float2 l0 = __half22float2(*(const __half2*)&u0.x);
        float2 h0 = __half22float2(*(const __half2*)&u0.y);
        a0 += w0 * l0.x;
        a1 += w0 * l0.y;
        a2 += w0 * h0.x;
        a3 += w0 * h0.y;
    }
    float di = dinv[n];
    int cb = 4 * c2;
    float va0 = di * a0 + b2[cb + 0];
    float va1 = di * a1 + b2[cb + 1];
    float va2 = di * a2 + b2[cb + 2];
    float va3 = (c2 == 0) ? (di * a3 + b2[3]) : -1e30f;
    float m = fmaxf(fmaxf(va0, va1), fmaxf(va2, va3));
    m = fmaxf(m, __shfl_xor(m, 1, 2));
    float s = __expf(va0 - m) + __expf(va1 - m) + __expf(va2 - m) + __expf(va3 - m);
    s += __shfl_xor(s, 1, 2);
    float lse = m + __logf(s);
    int base = n * NC + cb;
    out[base + 0] = va0 - lse;
    out[base + 1] = va1 - lse;
    out[base + 2] = va2 - lse;
    if (c2 == 0) out[base + 3] = va3 - lse;
}

extern "C" void kernel_launch(void* const* d_in, const int* in_sizes, int n_in,
                              void* d_out, int out_size, void* d_ws, size_t ws_size,
                              hipStream_t stream) {
    const float* x  = (const float*)d_in[0];
    const int*   ei = (const int*)d_in[1];
    const float* ew = (const float*)d_in[2];
    const float* W1 = (const float*)d_in[3];
    const float* b1 = (const float*)d_in[4];
    const float* W2 = (const float*)d_in[5];
    const float* b2 = (const float*)d_in[6];
    float* out = (float*)d_out;

    const int* srcp = ei;
    const int* dstp = ei + NE;

    // ws layout (4B units)
    float*  ws   = (float*)d_ws;
    float*  dinv = ws;                          // 100352
    __half* h1p  = (__half*)(ws + 100352);      // NN*16 halves = 800000 units
    __half* h2p  = (__half*)(ws + 900352);      // NN*8 halves = 400000 units
    int*    gcur = (int*)(ws + 1300352);        // 1024
    int*    rs   = (int*)(ws + 1301376);        // 100352
    int*    rc   = (int*)(ws + 1401728);        // 100352
    uint2*  ebuf = (uint2*)(ws + 1502080);      // NB*CAP uint2 = 7,206,912 units
    const unsigned* cbuf = (const unsigned*)ebuf;  // compact u32 overlay after k_sort

    auto cdiv = [](long long a, long long b) { return (int)((a + b - 1) / b); };

    hipMemsetAsync(gcur, 0, NB * sizeof(int), stream);
    k_append<<<AB, 1024, 0, stream>>>(srcp, dstp, ew, gcur, ebuf);
    k_sort<<<NB, 1024, 0, stream>>>(gcur, ebuf, rs, rc, dinv, x, W1, h1p);  // + fused proj1
    k_agg1p<<<cdiv((long long)NN * 4, 256), 256, 0, stream>>>(rs, rc, cbuf, h1p, dinv, b1, W2, h2p);
    k_agg2_lsm<<<cdiv((long long)NN * 2, 256), 256, 0, stream>>>(rs, rc, cbuf, h2p, dinv, b2, out);
}

// Round 10
// 213.145 us; speedup vs baseline: 3.1333x; 1.0176x over previous
//
#include <hip/hip_runtime.h>
#include <hip/hip_fp16.h>
#include <math.h>

// GCN 2-layer: N=100000 nodes, E=3200000 edges, 128 -> 16 -> 7
// R20 == R15 (empirical best, 213.2us): controlled revert after R16-R19
//      structural experiments (block residency, 5B records, LDS-atomic agg,
//      proj1 fusion) all measured neutral-to-negative.
//      Structure: LDS-staged coalesced append -> in-bucket counting sort +
//      dinv -> MFMA proj1 -> unroll-8 named-scalar agg kernels.
constexpr int NN = 100000;
constexpr int NE = 3200000;
constexpr int DF = 128;
constexpr int NH = 16;
constexpr int NC = 7;

constexpr int BN    = 256;                      // nodes per dst bucket (pow2)
constexpr int NB    = (NN + BN - 1) / BN;       // 391 buckets
constexpr int CAP   = 9216;                     // slots per bucket (mean 8184 + ~11 sigma)
constexpr int CHUNK = 4096;                     // edges per append block
constexpr int AB    = (NE + CHUNK - 1) / CHUNK; // 782
constexpr int EPT   = CHUNK / 1024;             // 4 edges per thread
constexpr int SPT   = (CAP + 1023) / 1024;      // 9 stash slots in sort

constexpr float QS   = 32767.0f;
constexpr float QINV = 1.0f / 32767.0f;

typedef _Float16 half8 __attribute__((ext_vector_type(8)));
typedef float    f32x4 __attribute__((ext_vector_type(4)));

// ---------------- bucket append: LDS chunk-local counting sort, coalesced flush ----------------
__global__ void __launch_bounds__(1024)
k_append(const int* __restrict__ src,
         const int* __restrict__ dst,
         const float* __restrict__ w,
         int* __restrict__ gcur,
         uint2* __restrict__ ebuf) {
    __shared__ int hist[NB];                 // per-bucket count in this chunk
    __shared__ int cscan[512];               // inclusive scan of hist (padded)
    __shared__ int basev[NB];                // global base for this chunk's run
    __shared__ int wsum[8];                  // wave partials for scan
    __shared__ uint2 staged[CHUNK];          // 32 KB: chunk edges grouped by bucket
    int tid = threadIdx.x;
    for (int i = tid; i < NB; i += 1024) hist[i] = 0;
    __syncthreads();
    int e0 = blockIdx.x * CHUNK;
    unsigned slo[EPT], sw[EPT];
    int sbr[EPT];
#pragma unroll
    for (int k = 0; k < EPT; ++k) {
        int e = e0 + tid + k * 1024;
        sbr[k] = -1;
        if (e < NE) {
            int d = __builtin_nontemporal_load(dst + e);
            int b = d >> 8;
            int r = atomicAdd(&hist[b], 1);             // the only per-edge atomic
            slo[k] = ((unsigned)(d & (BN - 1)) << 17) |
                     (unsigned)__builtin_nontemporal_load(src + e);
            unsigned q = (unsigned)(__builtin_nontemporal_load(w + e) * QS + 0.5f);
            sw[k]  = ((unsigned)b << 15) | q;           // b (9b) | q (15b)
            sbr[k] = (b << 13) | r;                     // b<391 (9b), r<4096 (13b)
        }
    }
    __syncthreads();
    // inclusive scan of hist over 512 entries: 8 fully-active waves, shfl_up
    {
        int v = 0;
        if (tid < 512) {
            v = (tid < NB) ? hist[tid] : 0;
#pragma unroll
            for (int d = 1; d < 64; d <<= 1) {
                int u = __shfl_up(v, d, 64);
                if ((tid & 63) >= d) v += u;
            }
            if ((tid & 63) == 63) wsum[tid >> 6] = v;
        }
        __syncthreads();
        if (tid == 0) {
            int acc = 0;
#pragma unroll
            for (int i = 0; i < 8; ++i) { int t = wsum[i]; wsum[i] = acc; acc += t; }
        }
        __syncthreads();
        if (tid < 512) cscan[tid] = v + wsum[tid >> 6];
    }
    __syncthreads();
    if (tid < NB) {
        int c = hist[tid];
        basev[tid] = (c > 0) ? atomicAdd(&gcur[tid], c) : 0;
    }
    __syncthreads();
    // stage: LDS scatter into bucket-grouped order
#pragma unroll
    for (int k = 0; k < EPT; ++k) {
        if (sbr[k] >= 0) {
            int b = sbr[k] >> 13;
            int idx = (cscan[b] - hist[b]) + (sbr[k] & 0x1FFF);
            uint2 v; v.x = slo[k]; v.y = sw[k];
            staged[idx] = v;
        }
    }
    __syncthreads();
    // flush: consecutive lanes write consecutive global slots within each bucket run
    int total = min(CHUNK, NE - e0);
    for (int i = tid; i < total; i += 1024) {
        uint2 sv = staged[i];
        int b = (int)(sv.y >> 15);
        int st = cscan[b] - hist[b];
        int pos = basev[b] + (i - st);
        if (pos < CAP) ebuf[(size_t)b * CAP + pos] = sv;
    }
}

// ---------------- intra-bucket counting sort: single LDS atomic/edge ----------------
__global__ void __launch_bounds__(1024)
k_sort(const int* __restrict__ gcur,
       uint2* __restrict__ ebuf,
       int* __restrict__ rs,
       int* __restrict__ rc,
       float* __restrict__ dinv) {
    __shared__ int cursor[BN];    // counts after loop1
    __shared__ int scanS[BN];
    __shared__ int startEx[BN];
    __shared__ int wsum[4];
    __shared__ unsigned sorted[CAP];  // 36 KB
    int b = blockIdx.x;
    int tid = threadIdx.x;
    int cnt = min(gcur[b], CAP);
    const uint2* eb = ebuf + (size_t)b * CAP;
    if (tid < BN) cursor[tid] = 0;
    __syncthreads();
    unsigned sval[SPT];
    int sdr[SPT];
#pragma unroll
    for (int k = 0; k < SPT; ++k) {
        int i = tid + k * 1024;
        sdr[k] = -1;
        if (i < cnt) {
            uint2 v = eb[i];
            int dl = (v.x >> 17) & (BN - 1);
            int r = atomicAdd(&cursor[dl], 1);          // the only per-edge atomic
            sval[k] = (v.x & 0x1FFFF) | ((v.y & 0x7FFFu) << 17);  // src | q
            sdr[k] = (dl << 14) | r;                    // dl (8b), r<9216 (14b)
        }
    }
    __syncthreads();
    // inclusive scan of cursor over 256 entries: 4 fully-active waves, shfl_up
    {
        int v = 0;
        if (tid < BN) {
            v = cursor[tid];
#pragma unroll
            for (int d = 1; d < 64; d <<= 1) {
                int u = __shfl_up(v, d, 64);
                if ((tid & 63) >= d) v += u;
            }
            if ((tid & 63) == 63) wsum[tid >> 6] = v;
        }
        __syncthreads();
        if (tid == 0) {
            int acc = 0;
#pragma unroll
            for (int i = 0; i < 4; ++i) { int t = wsum[i]; wsum[i] = acc; acc += t; }
        }
        __syncthreads();
        if (tid < BN) scanS[tid] = v + wsum[tid >> 6];
    }
    __syncthreads();
    if (tid < BN) {
        int ex = scanS[tid] - cursor[tid];
        startEx[tid] = ex;
        int n = b * BN + tid;
        if (n < NN) { rs[n] = b * CAP * 2 + ex; rc[n] = cursor[tid]; }  // u32 index
    }
    __syncthreads();
#pragma unroll
    for (int k = 0; k < SPT; ++k) {
        if (sdr[k] >= 0)
            sorted[startEx[sdr[k] >> 14] + (sdr[k] & 0x3FFF)] = sval[k];
    }
    __syncthreads();
    unsigned* eb32 = (unsigned*)ebuf + (size_t)b * CAP * 2;
    for (int i = tid; i < cnt; i += 1024) eb32[i] = sorted[i];
    // dinv: 4 threads per node, shfl-reduce
    {
        int node = tid >> 2, part = tid & 3;
        float s = (part == 0) ? 1.0f : 0.0f;  // self-loop
        int s0 = startEx[node], c = cursor[node];
        for (int i = part; i < c; i += 4) s += (float)(sorted[s0 + i] >> 17) * QINV;
        s += __shfl_xor(s, 1, 4);
        s += __shfl_xor(s, 2, 4);
        if (part == 0) {
            int n = b * BN + node;
            if (n < NN) dinv[n] = rsqrtf(s);
        }
    }
}

// ---------------- h1' = fp16( dinv * (x @ W1) ) via MFMA, 1 wave per 16 nodes ----------------
__global__ void __launch_bounds__(256)
k_proj1(const float* __restrict__ x,
        const float* __restrict__ W1,
        const float* __restrict__ dinv,
        __half* __restrict__ h1p) {
    int wave = threadIdx.x >> 6;
    int lane = threadIdx.x & 63;
    int tile = blockIdx.x * 4 + wave;
    if (tile * 16 >= NN) return;
    int m    = lane & 15;   // A row (node within tile); also B/C column (feature)
    int quad = lane >> 4;
    // B fragments: B[k][n] with n = lane&15, k = kc*32 + quad*8 + j
    half8 bfrag[4];
#pragma unroll
    for (int kc = 0; kc < 4; ++kc)
#pragma unroll
        for (int j = 0; j < 8; ++j)
            bfrag[kc][j] = (_Float16)W1[(kc * 32 + quad * 8 + j) * NH + m];
    int base = tile * 16;
    const float* xr = x + (size_t)(base + m) * DF + quad * 8;
    f32x4 acc = {0.f, 0.f, 0.f, 0.f};
#pragma unroll
    for (int kc = 0; kc < 4; ++kc) {
        const float4* p = (const float4*)(xr + kc * 32);
        float4 u0 = p[0];
        float4 u1 = p[1];
        half8 afrag;
        afrag[0] = (_Float16)u0.x; afrag[1] = (_Float16)u0.y;
        afrag[2] = (_Float16)u0.z; afrag[3] = (_Float16)u0.w;
        afrag[4] = (_Float16)u1.x; afrag[5] = (_Float16)u1.y;
        afrag[6] = (_Float16)u1.z; afrag[7] = (_Float16)u1.w;
        acc = __builtin_amdgcn_mfma_f32_16x16x32_f16(afrag, bfrag[kc], acc, 0, 0, 0);
    }
    // epilogue: D[row=quad*4+reg][col=m] * dinv[row] -> h1p[(base+row)*16 + m]
    float4 d4 = *(const float4*)(dinv + base + quad * 4);
#pragma unroll
    for (int reg = 0; reg < 4; ++reg) {
        float dd = (reg == 0) ? d4.x : (reg == 1) ? d4.y : (reg == 2) ? d4.z : d4.w;
        int row = quad * 4 + reg;
        h1p[(size_t)(base + row) * 16 + m] = __float2half(acc[reg] * dd);
    }
}

// ---------------- layer-1 aggregate + relu + proj2 fused (4 lanes/node, unroll-8 named) ----------------
__global__ void __launch_bounds__(256)
k_agg1p(const int* __restrict__ rs,
        const int* __restrict__ rc,
        const unsigned* __restrict__ cbuf,
        const __half* __restrict__ h1p,
        const float* __restrict__ dinv,
        const float* __restrict__ b1,
        const float* __restrict__ W2,
        __half* __restrict__ h2p) {
    const uint2* hp4 = (const uint2*)h1p;  // [NN*4], 4 halves each
    int t = blockIdx.x * 256 + threadIdx.x;
    int n = t >> 2;
    int f4 = t & 3;   // features 4*f4 .. 4*f4+3
    if (n >= NN) return;
    float a0, a1, a2, a3;
    {
        uint2 u = hp4[n * 4 + f4];  // self term
        float2 lo = __half22float2(*(const __half2*)&u.x);
        float2 hi = __half22float2(*(const __half2*)&u.y);
        a0 = lo.x; a1 = lo.y; a2 = hi.x; a3 = hi.y;
    }
    int s0 = rs[n], c = rc[n];
    int i = 0;
    for (; i + 7 < c; i += 8) {
        unsigned e0 = cbuf[s0 + i];
        unsigned e1 = cbuf[s0 + i + 1];
        unsigned e2 = cbuf[s0 + i + 2];
        unsigned e3 = cbuf[s0 + i + 3];
        unsigned e4 = cbuf[s0 + i + 4];
        unsigned e5 = cbuf[s0 + i + 5];
        unsigned e6 = cbuf[s0 + i + 6];
        unsigned e7 = cbuf[s0 + i + 7];
        uint2 u0 = hp4[(e0 & 0x1FFFF) * 4 + f4];
        uint2 u1 = hp4[(e1 & 0x1FFFF) * 4 + f4];
        uint2 u2 = hp4[(e2 & 0x1FFFF) * 4 + f4];
        uint2 u3 = hp4[(e3 & 0x1FFFF) * 4 + f4];
        uint2 u4 = hp4[(e4 & 0x1FFFF) * 4 + f4];
        uint2 u5 = hp4[(e5 & 0x1FFFF) * 4 + f4];
        uint2 u6 = hp4[(e6 & 0x1FFFF) * 4 + f4];
        uint2 u7 = hp4[(e7 & 0x1FFFF) * 4 + f4];
        float w0 = (float)(e0 >> 17) * QINV;
        float w1 = (float)(e1 >> 17) * QINV;
        float w2 = (float)(e2 >> 17) * QINV;
        float w3 = (float)(e3 >> 17) * QINV;
        float w4 = (float)(e4 >> 17) * QINV;
        float w5 = (float)(e5 >> 17) * QINV;
        float w6 = (float)(e6 >> 17) * QINV;
        float w7 = (float)(e7 >> 17) * QINV;
        float2 l0 = __half22float2(*(const __half2*)&u0.x);
        float2 h0 = __half22float2(*(const __half2*)&u0.y);
        float2 l1 = __half22float2(*(const __half2*)&u1.x);
        float2 h1v = __half22float2(*(const __half2*)&u1.y);
        float2 l2 = __half22float2(*(const __half2*)&u2.x);
        float2 h2v = __half22float2(*(const __half2*)&u2.y);
        float2 l3 = __half22float2(*(const __half2*)&u3.x);
        float2 h3v = __half22float2(*(const __half2*)&u3.y);
        float2 l4 = __half22float2(*(const __half2*)&u4.x);
        float2 h4v = __half22float2(*(const __half2*)&u4.y);
        float2 l5 = __half22float2(*(const __half2*)&u5.x);
        float2 h5v = __half22float2(*(const __half2*)&u5.y);
        float2 l6 = __half22float2(*(const __half2*)&u6.x);
        float2 h6v = __half22float2(*(const __half2*)&u6.y);
        float2 l7 = __half22float2(*(const __half2*)&u7.x);
        float2 h7v = __half22float2(*(const __half2*)&u7.y);
        a0 += w0 * l0.x + w1 * l1.x + w2 * l2.x + w3 * l3.x
            + w4 * l4.x + w5 * l5.x + w6 * l6.x + w7 * l7.x;
        a1 += w0 * l0.y + w1 * l1.y + w2 * l2.y + w3 * l3.y
            + w4 * l4.y + w5 * l5.y + w6 * l6.y + w7 * l7.y;
        a2 += w0 * h0.x + w1 * h1v.x + w2 * h2v.x + w3 * h3v.x
            + w4 * h4v.x + w5 * h5v.x + w6 * h6v.x + w7 * h7v.x;
        a3 += w0 * h0.y + w1 * h1v.y + w2 * h2v.y + w3 * h3v.y
            + w4 * h4v.y + w5 * h5v.y + w6 * h6v.y + w7 * h7v.y;
    }
    for (; i + 3 < c; i += 4) {
        unsigned e0 = cbuf[s0 + i];
        unsigned e1 = cbuf[s0 + i + 1];
        unsigned e2 = cbuf[s0 + i + 2];
        unsigned e3 = cbuf[s0 + i + 3];
        uint2 u0 = hp4[(e0 & 0x1FFFF) * 4 + f4];
        uint2 u1 = hp4[(e1 & 0x1FFFF) * 4 + f4];
        uint2 u2 = hp4[(e2 & 0x1FFFF) * 4 + f4];
        uint2 u3 = hp4[(e3 & 0x1FFFF) * 4 + f4];
        float w0 = (float)(e0 >> 17) * QINV;
        float w1 = (float)(e1 >> 17) * QINV;
        float w2 = (float)(e2 >> 17) * QINV;
        float w3 = (float)(e3 >> 17) * QINV;
        float2 l0 = __half22float2(*(const __half2*)&u0.x);
        float2 h0 = __half22float2(*(const __half2*)&u0.y);
        float2 l1 = __half22float2(*(const __half2*)&u1.x);
        float2 h1v = __half22float2(*(const __half2*)&u1.y);
        float2 l2 = __half22float2(*(const __half2*)&u2.x);
        float2 h2v = __half22float2(*(const __half2*)&u2.y);
        float2 l3 = __half22float2(*(const __half2*)&u3.x);
        float2 h3v = __half22float2(*(const __half2*)&u3.y);
        a0 += w0 * l0.x + w1 * l1.x + w2 * l2.x + w3 * l3.x;
        a1 += w0 * l0.y + w1 * l1.y + w2 * l2.y + w3 * l3.y;
        a2 += w0 * h0.x + w1 * h1v.x + w2 * h2v.x + w3 * h3v.x;
        a3 += w0 * h0.y + w1 * h1v.y + w2 * h2v.y + w3 * h3v.y;
    }
    for (; i < c; ++i) {
        unsigned e0 = cbuf[s0 + i];
        uint2 u0 = hp4[(e0 & 0x1FFFF) * 4 + f4];
        float w0 = (float)(e0 >> 17) * QINV;
        float2 l0 = __half22float2(*(const __half2*)&u0.x);
        float2 h0 = __half22float2(*(const __half2*)&u0.y);
        a0 += w0 * l0.x;
        a1 += w0 * l0.y;
        a2 += w0 * h0.x;
        a3 += w0 * h0.y;
    }
    // fused epilogue: out1 = di*a + b1, relu, @W2, *di -> h2p (fp16)
    float di = dinv[n];
    int fb = 4 * f4;
    float hr0 = fmaxf(di * a0 + b1[fb + 0], 0.0f);
    float hr1 = fmaxf(di * a1 + b1[fb + 1], 0.0f);
    float hr2 = fmaxf(di * a2 + b1[fb + 2], 0.0f);
    float hr3 = fmaxf(di * a3 + b1[fb + 3], 0.0f);
    float p0, p1, p2, p3, p4, p5, p6;
    {
        const float* w0r = W2 + (fb + 0) * NC;
        const float* w1r = W2 + (fb + 1) * NC;
        const float* w2r = W2 + (fb + 2) * NC;
        const float* w3r = W2 + (fb + 3) * NC;
        p0 = hr0 * w0r[0] + hr1 * w1r[0] + hr2 * w2r[0] + hr3 * w3r[0];
        p1 = hr0 * w0r[1] + hr1 * w1r[1] + hr2 * w2r[1] + hr3 * w3r[1];
        p2 = hr0 * w0r[2] + hr1 * w1r[2] + hr2 * w2r[2] + hr3 * w3r[2];
        p3 = hr0 * w0r[3] + hr1 * w1r[3] + hr2 * w2r[3] + hr3 * w3r[3];
        p4 = hr0 * w0r[4] + hr1 * w1r[4] + hr2 * w2r[4] + hr3 * w3r[4];
        p5 = hr0 * w0r[5] + hr1 * w1r[5] + hr2 * w2r[5] + hr3 * w3r[5];
        p6 = hr0 * w0r[6] + hr1 * w1r[6] + hr2 * w2r[6] + hr3 * w3r[6];
    }
#pragma unroll
    for (int mask = 1; mask < 4; mask <<= 1) {
        p0 += __shfl_xor(p0, mask, 4);
        p1 += __shfl_xor(p1, mask, 4);
        p2 += __shfl_xor(p2, mask, 4);
        p3 += __shfl_xor(p3, mask, 4);
        p4 += __shfl_xor(p4, mask, 4);
        p5 += __shfl_xor(p5, mask, 4);
        p6 += __shfl_xor(p6, mask, 4);
    }
    // lane f4 writes classes 2*f4, 2*f4+1 (lane 3 second = pad 0)
    float pa = (f4 == 0) ? p0 : (f4 == 1) ? p2 : (f4 == 2) ? p4 : p6;
    float pb = (f4 == 0) ? p1 : (f4 == 1) ? p3 : (f4 == 2) ? p5 : 0.0f;
    __half2 hv;
    hv.x = __float2half(di * pa);
    hv.y = __float2half(di * pb);
    ((__half2*)h2p)[n * 4 + f4] = hv;
}

// ---------------- layer-2 aggregate (2 lanes/node, unroll-8 named) + bias + log_softmax ----------------
__global__ void __launch_bounds__(256)
k_agg2_lsm(const int* __restrict__ rs,
           const int* __restrict__ rc,
           const unsigned* __restrict__ cbuf,
           const __half* __restrict__ h2p,
           const float* __restrict__ dinv,
           const float* __restrict__ b2,
           float* __restrict__ out) {
    const uint2* hp2 = (const uint2*)h2p;  // [NN*2], 4 halves each
    int t = blockIdx.x * 256 + threadIdx.x;
    int n = t >> 1;
    int c2 = t & 1;   // classes 4*c2 .. 4*c2+3 (lane1 last = pad)
    if (n >= NN) return;
    float a0, a1, a2, a3;
    {
        uint2 u = hp2[n * 2 + c2];  // self term (pad slot = 0)
        float2 lo = __half22float2(*(const __half2*)&u.x);
        float2 hi = __half22float2(*(const __half2*)&u.y);
        a0 = lo.x; a1 = lo.y; a2 = hi.x; a3 = hi.y;
    }
    int s0 = rs[n], c = rc[n];
    int i = 0;
    for (; i + 7 < c; i += 8) {
        unsigned e0 = cbuf[s0 + i];
        unsigned e1 = cbuf[s0 + i + 1];
        unsigned e2 = cbuf[s0 + i + 2];
        unsigned e3 = cbuf[s0 + i + 3];
        unsigned e4 = cbuf[s0 + i + 4];
        unsigned e5 = cbuf[s0 + i + 5];
        unsigned e6 = cbuf[s0 + i + 6];
        unsigned e7 = cbuf[s0 + i + 7];
        uint2 u0 = hp2[(e0 & 0x1FFFF) * 2 + c2];
        uint2 u1 = hp2[(e1 & 0x1FFFF) * 2 + c2];
        uint2 u2 = hp2[(e2 & 0x1FFFF) * 2 + c2];
        uint2 u3 = hp2[(e3 & 0x1FFFF) * 2 + c2];
        uint2 u4 = hp2[(e4 & 0x1FFFF) * 2 + c2];
        uint2 u5 = hp2[(e5 & 0x1FFFF) * 2 + c2];
        uint2 u6 = hp2[(e6 & 0x1FFFF) * 2 + c2];
        uint2 u7 = hp2[(e7 & 0x1FFFF) * 2 + c2];
        float w0 = (float)(e0 >> 17) * QINV;
        float w1 = (float)(e1 >> 17) * QINV;
        float w2 = (float)(e2 >> 17) * QINV;
        float w3 = (float)(e3 >> 17) * QINV;
        float w4 = (float)(e4 >> 17) * QINV;
        float w5 = (float)(e5 >> 17) * QINV;
        float w6 = (float)(e6 >> 17) * QINV;
        float w7 = (float)(e7 >> 17) * QINV;
        float2 l0 = __half22float2(*(const __half2*)&u0.x);
        float2 h0 = __half22float2(*(const __half2*)&u0.y);
        float2 l1 = __half22float2(*(const __half2*)&u1.x);
        float2 h1v = __half22float2(*(const __half2*)&u1.y);
        float2 l2 = __half22float2(*(const __half2*)&u2.x);
        float2 h2v = __half22float2(*(const __half2*)&u2.y);
        float2 l3 = __half22float2(*(const __half2*)&u3.x);
        float2 h3v = __half22float2(*(const __half2*)&u3.y);
        float2 l4 = __half22float2(*(const __half2*)&u4.x);
        float2 h4v = __half22float2(*(const __half2*)&u4.y);
        float2 l5 = __half22float2(*(const __half2*)&u5.x);
        float2 h5v = __half22float2(*(const __half2*)&u5.y);
        float2 l6 = __half22float2(*(const __half2*)&u6.x);
        float2 h6v = __half22float2(*(const __half2*)&u6.y);
        float2 l7 = __half22float2(*(const __half2*)&u7.x);
        float2 h7v = __half22float2(*(const __half2*)&u7.y);
        a0 += w0 * l0.x + w1 * l1.x + w2 * l2.x + w3 * l3.x
            + w4 * l4.x + w5 * l5.x + w6 * l6.x + w7 * l7.x;
        a1 += w0 * l0.y + w1 * l1.y + w2 * l2.y + w3 * l3.y
            + w4 * l4.y + w5 * l5.y + w6 * l6.y + w7 * l7.y;
        a2 += w0 * h0.x + w1 * h1v.x + w2 * h2v.x + w3 * h3v.x
            + w4 * h4v.x + w5 * h5v.x + w6 * h6v.x + w7 * h7v.x;
        a3 += w0 * h0.y + w1 * h1v.y + w2 * h2v.y + w3 * h3v.y
            + w4 * h4v.y + w5 * h5v.y + w6 * h6v.y + w7 * h7v.y;
    }
    for (; i + 3 < c; i += 4) {
        unsigned e0 = cbuf[s0 + i];
        unsigned e1 = cbuf[s0 + i + 1];
        unsigned e2 = cbuf[s0 + i + 2];
        unsigned e3 = cbuf[s0 + i + 3];
        uint2 u0 = hp2[(e0 & 0x1FFFF) * 2 + c2];
        uint2 u1 = hp2[(e1 & 0x1FFFF) * 2 + c2];
        uint2 u2 = hp2[(e2 & 0x1FFFF) * 2 + c2];
        uint2 u3 = hp2[(e3 & 0x1FFFF) * 2 + c2];
        float w0 = (float)(e0 >> 17) * QINV;
        float w1 = (float)(e1 >> 17) * QINV;
        float w2 = (float)(e2 >> 17) * QINV;
        float w3 = (float)(e3 >> 17) * QINV;
        float2 l0 = __half22float2(*(const __half2*)&u0.x);
        float2 h0 = __half22float2(*(const __half2*)&u0.y);
        float2 l1 = __half22float2(*(const __half2*)&u1.x);
        float2 h1v = __half22float2(*(const __half2*)&u1.y);
        float2 l2 = __half22float2(*(const __half2*)&u2.x);
        float2 h2v = __half22float2(*(const __half2*)&u2.y);
        float2 l3 = __half22float2(*(const __half2*)&u3.x);
        float2 h3v = __half22float2(*(const __half2*)&u3.y);
        a0 += w0 * l0.x + w1 * l1.x + w2 * l2.x + w3 * l3.x;
        a1 += w0 * l0.y + w1 * l1.y + w2 * l2.y + w3 * l3.y;
        a2 += w0 * h0.x + w1 * h1v.x + w2 * h2v.x + w3 * h3v.x;
        a3 += w0 * h0.y + w1 * h1v.y + w2 * h2v.y + w3 * h3v.y;
    }
    for (; i < c; ++i) {
        unsigned e0 = cbuf[s0 + i];
        uint2 u0 = hp2[(e0 & 0x1FFFF) * 2 + c2];
        float w0 = (float)(e0 >> 17) * QINV;
        float2 l0 = __half22float2(*(const __half2*)&u0.x);
        float2 h0 = __half22float2(*(const __half2*)&u0.y);
        a0 += w0 * l0.x;
        a1 += w0 * l0.y;
        a2 += w0 * h0.x;
        a3 += w0 * h0.y;
    }
    float di = dinv[n];
    int cb = 4 * c2;
    float va0 = di * a0 + b2[cb + 0];
    float va1 = di * a1 + b2[cb + 1];
    float va2 = di * a2 + b2[cb + 2];
    float va3 = (c2 == 0) ? (di * a3 + b2[3]) : -1e30f;
    float m = fmaxf(fmaxf(va0, va1), fmaxf(va2, va3));
    m = fmaxf(m, __shfl_xor(m, 1, 2));
    float s = __expf(va0 - m) + __expf(va1 - m) + __expf(va2 - m) + __expf(va3 - m);
    s += __shfl_xor(s, 1, 2);
    float lse = m + __logf(s);
    int base = n * NC + cb;
    out[base + 0] = va0 - lse;
    out[base + 1] = va1 - lse;
    out[base + 2] = va2 - lse;
    if (c2 == 0) out[base + 3] = va3 - lse;
}

extern "C" void kernel_launch(void* const* d_in, const int* in_sizes, int n_in,
                              void* d_out, int out_size, void* d_ws, size_t ws_size,
                              hipStream_t stream) {
    const float* x  = (const float*)d_in[0];
    const int*   ei = (const int*)d_in[1];
    const float* ew = (const float*)d_in[2];
    const float* W1 = (const float*)d_in[3];
    const float* b1 = (const float*)d_in[4];
    const float* W2 = (const float*)d_in[5];
    const float* b2 = (const float*)d_in[6];
    float* out = (float*)d_out;

    const int* srcp = ei;
    const int* dstp = ei + NE;

    // ws layout (4B units)
    float*  ws   = (float*)d_ws;
    float*  dinv = ws;                          // 100352
    __half* h1p  = (__half*)(ws + 100352);      // NN*16 halves = 800000 units
    __half* h2p  = (__half*)(ws + 900352);      // NN*8 halves = 400000 units
    int*    gcur = (int*)(ws + 1300352);        // 1024
    int*    rs   = (int*)(ws + 1301376);        // 100352
    int*    rc   = (int*)(ws + 1401728);        // 100352
    uint2*  ebuf = (uint2*)(ws + 1502080);      // NB*CAP uint2 = 7,206,912 units
    const unsigned* cbuf = (const unsigned*)ebuf;  // compact u32 overlay after k_sort

    auto cdiv = [](long long a, long long b) { return (int)((a + b - 1) / b); };

    hipMemsetAsync(gcur, 0, NB * sizeof(int), stream);
    k_append<<<AB, 1024, 0, stream>>>(srcp, dstp, ew, gcur, ebuf);
    k_sort<<<NB, 1024, 0, stream>>>(gcur, ebuf, rs, rc, dinv);
    k_proj1<<<cdiv(NN, 64), 256, 0, stream>>>(x, W1, dinv, h1p);  // 1563 blocks, 4 tiles each
    k_agg1p<<<cdiv((long long)NN * 4, 256), 256, 0, stream>>>(rs, rc, cbuf, h1p, dinv, b1, W2, h2p);
    k_agg2_lsm<<<cdiv((long long)NN * 2, 256), 256, 0, stream>>>(rs, rc, cbuf, h2p, dinv, b2, out);
}

// Round 11
// 211.197 us; speedup vs baseline: 3.1622x; 1.0092x over previous
//
#include <hip/hip_runtime.h>
#include <hip/hip_fp16.h>
#include <math.h>

// GCN 2-layer: N=100000 nodes, E=3200000 edges, 128 -> 16 -> 7
// R21: R20 base (== R15 best, 213.1us) + software-pipelined agg loops:
//      batch k's gathers issue, then batch k+1's 8 index loads issue BEFORE
//      batch k's math -> index-load latency (~200cy) hides under gathers+math.
//      Only mechanism with a proven win on these kernels is MLP (R14/R15);
//      this is its last untested increment. All else identical to R20.
constexpr int NN = 100000;
constexpr int NE = 3200000;
constexpr int DF = 128;
constexpr int NH = 16;
constexpr int NC = 7;

constexpr int BN    = 256;                      // nodes per dst bucket (pow2)
constexpr int NB    = (NN + BN - 1) / BN;       // 391 buckets
constexpr int CAP   = 9216;                     // slots per bucket (mean 8184 + ~11 sigma)
constexpr int CHUNK = 4096;                     // edges per append block
constexpr int AB    = (NE + CHUNK - 1) / CHUNK; // 782
constexpr int EPT   = CHUNK / 1024;             // 4 edges per thread
constexpr int SPT   = (CAP + 1023) / 1024;      // 9 stash slots in sort

constexpr float QS   = 32767.0f;
constexpr float QINV = 1.0f / 32767.0f;

typedef _Float16 half8 __attribute__((ext_vector_type(8)));
typedef float    f32x4 __attribute__((ext_vector_type(4)));

// ---------------- bucket append: LDS chunk-local counting sort, coalesced flush ----------------
__global__ void __launch_bounds__(1024)
k_append(const int* __restrict__ src,
         const int* __restrict__ dst,
         const float* __restrict__ w,
         int* __restrict__ gcur,
         uint2* __restrict__ ebuf) {
    __shared__ int hist[NB];                 // per-bucket count in this chunk
    __shared__ int cscan[512];               // inclusive scan of hist (padded)
    __shared__ int basev[NB];                // global base for this chunk's run
    __shared__ int wsum[8];                  // wave partials for scan
    __shared__ uint2 staged[CHUNK];          // 32 KB: chunk edges grouped by bucket
    int tid = threadIdx.x;
    for (int i = tid; i < NB; i += 1024) hist[i] = 0;
    __syncthreads();
    int e0 = blockIdx.x * CHUNK;
    unsigned slo[EPT], sw[EPT];
    int sbr[EPT];
#pragma unroll
    for (int k = 0; k < EPT; ++k) {
        int e = e0 + tid + k * 1024;
        sbr[k] = -1;
        if (e < NE) {
            int d = __builtin_nontemporal_load(dst + e);
            int b = d >> 8;
            int r = atomicAdd(&hist[b], 1);             // the only per-edge atomic
            slo[k] = ((unsigned)(d & (BN - 1)) << 17) |
                     (unsigned)__builtin_nontemporal_load(src + e);
            unsigned q = (unsigned)(__builtin_nontemporal_load(w + e) * QS + 0.5f);
            sw[k]  = ((unsigned)b << 15) | q;           // b (9b) | q (15b)
            sbr[k] = (b << 13) | r;                     // b<391 (9b), r<4096 (13b)
        }
    }
    __syncthreads();
    // inclusive scan of hist over 512 entries: 8 fully-active waves, shfl_up
    {
        int v = 0;
        if (tid < 512) {
            v = (tid < NB) ? hist[tid] : 0;
#pragma unroll
            for (int d = 1; d < 64; d <<= 1) {
                int u = __shfl_up(v, d, 64);
                if ((tid & 63) >= d) v += u;
            }
            if ((tid & 63) == 63) wsum[tid >> 6] = v;
        }
        __syncthreads();
        if (tid == 0) {
            int acc = 0;
#pragma unroll
            for (int i = 0; i < 8; ++i) { int t = wsum[i]; wsum[i] = acc; acc += t; }
        }
        __syncthreads();
        if (tid < 512) cscan[tid] = v + wsum[tid >> 6];
    }
    __syncthreads();
    if (tid < NB) {
        int c = hist[tid];
        basev[tid] = (c > 0) ? atomicAdd(&gcur[tid], c) : 0;
    }
    __syncthreads();
    // stage: LDS scatter into bucket-grouped order
#pragma unroll
    for (int k = 0; k < EPT; ++k) {
        if (sbr[k] >= 0) {
            int b = sbr[k] >> 13;
            int idx = (cscan[b] - hist[b]) + (sbr[k] & 0x1FFF);
            uint2 v; v.x = slo[k]; v.y = sw[k];
            staged[idx] = v;
        }
    }
    __syncthreads();
    // flush: consecutive lanes write consecutive global slots within each bucket run
    int total = min(CHUNK, NE - e0);
    for (int i = tid; i < total; i += 1024) {
        uint2 sv = staged[i];
        int b = (int)(sv.y >> 15);
        int st = cscan[b] - hist[b];
        int pos = basev[b] + (i - st);
        if (pos < CAP) ebuf[(size_t)b * CAP + pos] = sv;
    }
}

// ---------------- intra-bucket counting sort: single LDS atomic/edge ----------------
__global__ void __launch_bounds__(1024)
k_sort(const int* __restrict__ gcur,
       uint2* __restrict__ ebuf,
       int* __restrict__ rs,
       int* __restrict__ rc,
       float* __restrict__ dinv) {
    __shared__ int cursor[BN];    // counts after loop1
    __shared__ int scanS[BN];
    __shared__ int startEx[BN];
    __shared__ int wsum[4];
    __shared__ unsigned sorted[CAP];  // 36 KB
    int b = blockIdx.x;
    int tid = threadIdx.x;
    int cnt = min(gcur[b], CAP);
    const uint2* eb = ebuf + (size_t)b * CAP;
    if (tid < BN) cursor[tid] = 0;
    __syncthreads();
    unsigned sval[SPT];
    int sdr[SPT];
#pragma unroll
    for (int k = 0; k < SPT; ++k) {
        int i = tid + k * 1024;
        sdr[k] = -1;
        if (i < cnt) {
            uint2 v = eb[i];
            int dl = (v.x >> 17) & (BN - 1);
            int r = atomicAdd(&cursor[dl], 1);          // the only per-edge atomic
            sval[k] = (v.x & 0x1FFFF) | ((v.y & 0x7FFFu) << 17);  // src | q
            sdr[k] = (dl << 14) | r;                    // dl (8b), r<9216 (14b)
        }
    }
    __syncthreads();
    // inclusive scan of cursor over 256 entries: 4 fully-active waves, shfl_up
    {
        int v = 0;
        if (tid < BN) {
            v = cursor[tid];
#pragma unroll
            for (int d = 1; d < 64; d <<= 1) {
                int u = __shfl_up(v, d, 64);
                if ((tid & 63) >= d) v += u;
            }
            if ((tid & 63) == 63) wsum[tid >> 6] = v;
        }
        __syncthreads();
        if (tid == 0) {
            int acc = 0;
#pragma unroll
            for (int i = 0; i < 4; ++i) { int t = wsum[i]; wsum[i] = acc; acc += t; }
        }
        __syncthreads();
        if (tid < BN) scanS[tid] = v + wsum[tid >> 6];
    }
    __syncthreads();
    if (tid < BN) {
        int ex = scanS[tid] - cursor[tid];
        startEx[tid] = ex;
        int n = b * BN + tid;
        if (n < NN) { rs[n] = b * CAP * 2 + ex; rc[n] = cursor[tid]; }  // u32 index
    }
    __syncthreads();
#pragma unroll
    for (int k = 0; k < SPT; ++k) {
        if (sdr[k] >= 0)
            sorted[startEx[sdr[k] >> 14] + (sdr[k] & 0x3FFF)] = sval[k];
    }
    __syncthreads();
    unsigned* eb32 = (unsigned*)ebuf + (size_t)b * CAP * 2;
    for (int i = tid; i < cnt; i += 1024) eb32[i] = sorted[i];
    // dinv: 4 threads per node, shfl-reduce
    {
        int node = tid >> 2, part = tid & 3;
        float s = (part == 0) ? 1.0f : 0.0f;  // self-loop
        int s0 = startEx[node], c = cursor[node];
        for (int i = part; i < c; i += 4) s += (float)(sorted[s0 + i] >> 17) * QINV;
        s += __shfl_xor(s, 1, 4);
        s += __shfl_xor(s, 2, 4);
        if (part == 0) {
            int n = b * BN + node;
            if (n < NN) dinv[n] = rsqrtf(s);
        }
    }
}

// ---------------- h1' = fp16( dinv * (x @ W1) ) via MFMA, 1 wave per 16 nodes ----------------
__global__ void __launch_bounds__(256)
k_proj1(const float* __restrict__ x,
        const float* __restrict__ W1,
        const float* __restrict__ dinv,
        __half* __restrict__ h1p) {
    int wave = threadIdx.x >> 6;
    int lane = threadIdx.x & 63;
    int tile = blockIdx.x * 4 + wave;
    if (tile * 16 >= NN) return;
    int m    = lane & 15;   // A row (node within tile); also B/C column (feature)
    int quad = lane >> 4;
    // B fragments: B[k][n] with n = lane&15, k = kc*32 + quad*8 + j
    half8 bfrag[4];
#pragma unroll
    for (int kc = 0; kc < 4; ++kc)
#pragma unroll
        for (int j = 0; j < 8; ++j)
            bfrag[kc][j] = (_Float16)W1[(kc * 32 + quad * 8 + j) * NH + m];
    int base = tile * 16;
    const float* xr = x + (size_t)(base + m) * DF + quad * 8;
    f32x4 acc = {0.f, 0.f, 0.f, 0.f};
#pragma unroll
    for (int kc = 0; kc < 4; ++kc) {
        const float4* p = (const float4*)(xr + kc * 32);
        float4 u0 = p[0];
        float4 u1 = p[1];
        half8 afrag;
        afrag[0] = (_Float16)u0.x; afrag[1] = (_Float16)u0.y;
        afrag[2] = (_Float16)u0.z; afrag[3] = (_Float16)u0.w;
        afrag[4] = (_Float16)u1.x; afrag[5] = (_Float16)u1.y;
        afrag[6] = (_Float16)u1.z; afrag[7] = (_Float16)u1.w;
        acc = __builtin_amdgcn_mfma_f32_16x16x32_f16(afrag, bfrag[kc], acc, 0, 0, 0);
    }
    // epilogue: D[row=quad*4+reg][col=m] * dinv[row] -> h1p[(base+row)*16 + m]
    float4 d4 = *(const float4*)(dinv + base + quad * 4);
#pragma unroll
    for (int reg = 0; reg < 4; ++reg) {
        float dd = (reg == 0) ? d4.x : (reg == 1) ? d4.y : (reg == 2) ? d4.z : d4.w;
        int row = quad * 4 + reg;
        h1p[(size_t)(base + row) * 16 + m] = __float2half(acc[reg] * dd);
    }
}

// ---------------- layer-1 aggregate + relu + proj2 fused (4 lanes/node, sw-pipelined batches of 8) ----------------
__global__ void __launch_bounds__(256)
k_agg1p(const int* __restrict__ rs,
        const int* __restrict__ rc,
        const unsigned* __restrict__ cbuf,
        const __half* __restrict__ h1p,
        const float* __restrict__ dinv,
        const float* __restrict__ b1,
        const float* __restrict__ W2,
        __half* __restrict__ h2p) {
    const uint2* hp4 = (const uint2*)h1p;  // [NN*4], 4 halves each
    int t = blockIdx.x * 256 + threadIdx.x;
    int n = t >> 2;
    int f4 = t & 3;   // features 4*f4 .. 4*f4+3
    if (n >= NN) return;
    float a0, a1, a2, a3;
    {
        uint2 u = hp4[n * 4 + f4];  // self term
        float2 lo = __half22float2(*(const __half2*)&u.x);
        float2 hi = __half22float2(*(const __half2*)&u.y);
        a0 = lo.x; a1 = lo.y; a2 = hi.x; a3 = hi.y;
    }
    int s0 = rs[n], c = rc[n];
    int i = 0;
    if (c >= 8) {
        // pipeline prologue: batch-0 indices in registers
        unsigned e0 = cbuf[s0 + 0];
        unsigned e1 = cbuf[s0 + 1];
        unsigned e2 = cbuf[s0 + 2];
        unsigned e3 = cbuf[s0 + 3];
        unsigned e4 = cbuf[s0 + 4];
        unsigned e5 = cbuf[s0 + 5];
        unsigned e6 = cbuf[s0 + 6];
        unsigned e7 = cbuf[s0 + 7];
        for (; i + 15 < c; i += 8) {
            // gathers for current batch (issue first)
            uint2 u0 = hp4[(e0 & 0x1FFFF) * 4 + f4];
            uint2 u1 = hp4[(e1 & 0x1FFFF) * 4 + f4];
            uint2 u2 = hp4[(e2 & 0x1FFFF) * 4 + f4];
            uint2 u3 = hp4[(e3 & 0x1FFFF) * 4 + f4];
            uint2 u4 = hp4[(e4 & 0x1FFFF) * 4 + f4];
            uint2 u5 = hp4[(e5 & 0x1FFFF) * 4 + f4];
            uint2 u6 = hp4[(e6 & 0x1FFFF) * 4 + f4];
            uint2 u7 = hp4[(e7 & 0x1FFFF) * 4 + f4];
            // prefetch next batch's indices (hide under gathers + math)
            unsigned g0 = cbuf[s0 + i + 8];
            unsigned g1 = cbuf[s0 + i + 9];
            unsigned g2 = cbuf[s0 + i + 10];
            unsigned g3 = cbuf[s0 + i + 11];
            unsigned g4 = cbuf[s0 + i + 12];
            unsigned g5 = cbuf[s0 + i + 13];
            unsigned g6 = cbuf[s0 + i + 14];
            unsigned g7 = cbuf[s0 + i + 15];
            // math for current batch
            float w0 = (float)(e0 >> 17) * QINV;
            float w1 = (float)(e1 >> 17) * QINV;
            float w2 = (float)(e2 >> 17) * QINV;
            float w3 = (float)(e3 >> 17) * QINV;
            float w4 = (float)(e4 >> 17) * QINV;
            float w5 = (float)(e5 >> 17) * QINV;
            float w6 = (float)(e6 >> 17) * QINV;
            float w7 = (float)(e7 >> 17) * QINV;
            float2 l0 = __half22float2(*(const __half2*)&u0.x);
            float2 h0 = __half22float2(*(const __half2*)&u0.y);
            float2 l1 = __half22float2(*(const __half2*)&u1.x);
            float2 h1v = __half22float2(*(const __half2*)&u1.y);
            float2 l2 = __half22float2(*(const __half2*)&u2.x);
            float2 h2v = __half22float2(*(const __half2*)&u2.y);
            float2 l3 = __half22float2(*(const __half2*)&u3.x);
            float2 h3v = __half22float2(*(const __half2*)&u3.y);
            float2 l4 = __half22float2(*(const __half2*)&u4.x);
            float2 h4v = __half22float2(*(const __half2*)&u4.y);
            float2 l5 = __half22float2(*(const __half2*)&u5.x);
            float2 h5v = __half22float2(*(const __half2*)&u5.y);
            float2 l6 = __half22float2(*(const __half2*)&u6.x);
            float2 h6v = __half22float2(*(const __half2*)&u6.y);
            float2 l7 = __half22float2(*(const __half2*)&u7.x);
            float2 h7v = __half22float2(*(const __half2*)&u7.y);
            a0 += w0 * l0.x + w1 * l1.x + w2 * l2.x + w3 * l3.x
                + w4 * l4.x + w5 * l5.x + w6 * l6.x + w7 * l7.x;
            a1 += w0 * l0.y + w1 * l1.y + w2 * l2.y + w3 * l3.y
                + w4 * l4.y + w5 * l5.y + w6 * l6.y + w7 * l7.y;
            a2 += w0 * h0.x + w1 * h1v.x + w2 * h2v.x + w3 * h3v.x
                + w4 * h4v.x + w5 * h5v.x + w6 * h6v.x + w7 * h7v.x;
            a3 += w0 * h0.y + w1 * h1v.y + w2 * h2v.y + w3 * h3v.y
                + w4 * h4v.y + w5 * h5v.y + w6 * h6v.y + w7 * h7v.y;
            e0 = g0; e1 = g1; e2 = g2; e3 = g3;
            e4 = g4; e5 = g5; e6 = g6; e7 = g7;
        }
        // pipeline epilogue: final full batch (indices already in registers)
        {
            uint2 u0 = hp4[(e0 & 0x1FFFF) * 4 + f4];
            uint2 u1 = hp4[(e1 & 0x1FFFF) * 4 + f4];
            uint2 u2 = hp4[(e2 & 0x1FFFF) * 4 + f4];
            uint2 u3 = hp4[(e3 & 0x1FFFF) * 4 + f4];
            uint2 u4 = hp4[(e4 & 0x1FFFF) * 4 + f4];
            uint2 u5 = hp4[(e5 & 0x1FFFF) * 4 + f4];
            uint2 u6 = hp4[(e6 & 0x1FFFF) * 4 + f4];
            uint2 u7 = hp4[(e7 & 0x1FFFF) * 4 + f4];
            float w0 = (float)(e0 >> 17) * QINV;
            float w1 = (float)(e1 >> 17) * QINV;
            float w2 = (float)(e2 >> 17) * QINV;
            float w3 = (float)(e3 >> 17) * QINV;
            float w4 = (float)(e4 >> 17) * QINV;
            float w5 = (float)(e5 >> 17) * QINV;
            float w6 = (float)(e6 >> 17) * QINV;
            float w7 = (float)(e7 >> 17) * QINV;
            float2 l0 = __half22float2(*(const __half2*)&u0.x);
            float2 h0 = __half22float2(*(const __half2*)&u0.y);
            float2 l1 = __half22float2(*(const __half2*)&u1.x);
            float2 h1v = __half22float2(*(const __half2*)&u1.y);
            float2 l2 = __half22float2(*(const __half2*)&u2.x);
            float2 h2v = __half22float2(*(const __half2*)&u2.y);
            float2 l3 = __half22float2(*(const __half2*)&u3.x);
            float2 h3v = __half22float2(*(const __half2*)&u3.y);
            float2 l4 = __half22float2(*(const __half2*)&u4.x);
            float2 h4v = __half22float2(*(const __half2*)&u4.y);
            float2 l5 = __half22float2(*(const __half2*)&u5.x);
            float2 h5v = __half22float2(*(const __half2*)&u5.y);
            float2 l6 = __half22float2(*(const __half2*)&u6.x);
            float2 h6v = __half22float2(*(const __half2*)&u6.y);
            float2 l7 = __half22float2(*(const __half2*)&u7.x);
            float2 h7v = __half22float2(*(const __half2*)&u7.y);
            a0 += w0 * l0.x + w1 * l1.x + w2 * l2.x + w3 * l3.x
                + w4 * l4.x + w5 * l5.x + w6 * l6.x + w7 * l7.x;
            a1 += w0 * l0.y + w1 * l1.y + w2 * l2.y + w3 * l3.y
                + w4 * l4.y + w5 * l5.y + w6 * l6.y + w7 * l7.y;
            a2 += w0 * h0.x + w1 * h1v.x + w2 * h2v.x + w3 * h3v.x
                + w4 * h4v.x + w5 * h5v.x + w6 * h6v.x + w7 * h7v.x;
            a3 += w0 * h0.y + w1 * h1v.y + w2 * h2v.y + w3 * h3v.y
                + w4 * h4v.y + w5 * h5v.y + w6 * h6v.y + w7 * h7v.y;
            i += 8;
        }
    }
    for (; i + 3 < c; i += 4) {
        unsigned e0 = cbuf[s0 + i];
        unsigned e1 = cbuf[s0 + i + 1];
        unsigned e2 = cbuf[s0 + i + 2];
        unsigned e3 = cbuf[s0 + i + 3];
        uint2 u0 = hp4[(e0 & 0x1FFFF) * 4 + f4];
        uint2 u1 = hp4[(e1 & 0x1FFFF) * 4 + f4];
        uint2 u2 = hp4[(e2 & 0x1FFFF) * 4 + f4];
        uint2 u3 = hp4[(e3 & 0x1FFFF) * 4 + f4];
        float w0 = (float)(e0 >> 17) * QINV;
        float w1 = (float)(e1 >> 17) * QINV;
        float w2 = (float)(e2 >> 17) * QINV;
        float w3 = (float)(e3 >> 17) * QINV;
        float2 l0 = __half22float2(*(const __half2*)&u0.x);
        float2 h0 = __half22float2(*(const __half2*)&u0.y);
        float2 l1 = __half22float2(*(const __half2*)&u1.x);
        float2 h1v = __half22float2(*(const __half2*)&u1.y);
        float2 l2 = __half22float2(*(const __half2*)&u2.x);
        float2 h2v = __half22float2(*(const __half2*)&u2.y);
        float2 l3 = __half22float2(*(const __half2*)&u3.x);
        float2 h3v = __half22float2(*(const __half2*)&u3.y);
        a0 += w0 * l0.x + w1 * l1.x + w2 * l2.x + w3 * l3.x;
        a1 += w0 * l0.y + w1 * l1.y + w2 * l2.y + w3 * l3.y;
        a2 += w0 * h0.x + w1 * h1v.x + w2 * h2v.x + w3 * h3v.x;
        a3 += w0 * h0.y + w1 * h1v.y + w2 * h2v.y + w3 * h3v.y;
    }
    for (; i < c; ++i) {
        unsigned e0 = cbuf[s0 + i];
        uint2 u0 = hp4[(e0 & 0x1FFFF) * 4 + f4];
        float w0 = (float)(e0 >> 17) * QINV;
        float2 l0 = __half22float2(*(const __half2*)&u0.x);
        float2 h0 = __half22float2(*(const __half2*)&u0.y);
        a0 += w0 * l0.x;
        a1 += w0 * l0.y;
        a2 += w0 * h0.x;
        a3 += w0 * h0.y;
    }
    // fused epilogue: out1 = di*a + b1, relu, @W2, *di -> h2p (fp16)
    float di = dinv[n];
    int fb = 4 * f4;
    float hr0 = fmaxf(di * a0 + b1[fb + 0], 0.0f);
    float hr1 = fmaxf(di * a1 + b1[fb + 1], 0.0f);
    float hr2 = fmaxf(di * a2 + b1[fb + 2], 0.0f);
    float hr3 = fmaxf(di * a3 + b1[fb + 3], 0.0f);
    float p0, p1, p2, p3, p4, p5, p6;
    {
        const float* w0r = W2 + (fb + 0) * NC;
        const float* w1r = W2 + (fb + 1) * NC;
        const float* w2r = W2 + (fb + 2) * NC;
        const float* w3r = W2 + (fb + 3) * NC;
        p0 = hr0 * w0r[0] + hr1 * w1r[0] + hr2 * w2r[0] + hr3 * w3r[0];
        p1 = hr0 * w0r[1] + hr1 * w1r[1] + hr2 * w2r[1] + hr3 * w3r[1];
        p2 = hr0 * w0r[2] + hr1 * w1r[2] + hr2 * w2r[2] + hr3 * w3r[2];
        p3 = hr0 * w0r[3] + hr1 * w1r[3] + hr2 * w2r[3] + hr3 * w3r[3];
        p4 = hr0 * w0r[4] + hr1 * w1r[4] + hr2 * w2r[4] + hr3 * w3r[4];
        p5 = hr0 * w0r[5] + hr1 * w1r[5] + hr2 * w2r[5] + hr3 * w3r[5];
        p6 = hr0 * w0r[6] + hr1 * w1r[6] + hr2 * w2r[6] + hr3 * w3r[6];
    }
#pragma unroll
    for (int mask = 1; mask < 4; mask <<= 1) {
        p0 += __shfl_xor(p0, mask, 4);
        p1 += __shfl_xor(p1, mask, 4);
        p2 += __shfl_xor(p2, mask, 4);
        p3 += __shfl_xor(p3, mask, 4);
        p4 += __shfl_xor(p4, mask, 4);
        p5 += __shfl_xor(p5, mask, 4);
        p6 += __shfl_xor(p6, mask, 4);
    }
    // lane f4 writes classes 2*f4, 2*f4+1 (lane 3 second = pad 0)
    float pa = (f4 == 0) ? p0 : (f4 == 1) ? p2 : (f4 == 2) ? p4 : p6;
    float pb = (f4 == 0) ? p1 : (f4 == 1) ? p3 : (f4 == 2) ? p5 : 0.0f;
    __half2 hv;
    hv.x = __float2half(di * pa);
    hv.y = __float2half(di * pb);
    ((__half2*)h2p)[n * 4 + f4] = hv;
}

// ---------------- layer-2 aggregate (2 lanes/node, sw-pipelined batches of 8) + bias + log_softmax ----------------
__global__ void __launch_bounds__(256)
k_agg2_lsm(const int* __restrict__ rs,
           const int* __restrict__ rc,
           const unsigned* __restrict__ cbuf,
           const __half* __restrict__ h2p,
           const float* __restrict__ dinv,
           const float* __restrict__ b2,
           float* __restrict__ out) {
    const uint2* hp2 = (const uint2*)h2p;  // [NN*2], 4 halves each
    int t = blockIdx.x * 256 + threadIdx.x;
    int n = t >> 1;
    int c2 = t & 1;   // classes 4*c2 .. 4*c2+3 (lane1 last = pad)
    if (n >= NN) return;
    float a0, a1, a2, a3;
    {
        uint2 u = hp2[n * 2 + c2];  // self term (pad slot = 0)
        float2 lo = __half22float2(*(const __half2*)&u.x);
        float2 hi = __half22float2(*(const __half2*)&u.y);
        a0 = lo.x; a1 = lo.y; a2 = hi.x; a3 = hi.y;
    }
    int s0 = rs[n], c = rc[n];
    int i = 0;
    if (c >= 8) {
        unsigned e0 = cbuf[s0 + 0];
        unsigned e1 = cbuf[s0 + 1];
        unsigned e2 = cbuf[s0 + 2];
        unsigned e3 = cbuf[s0 + 3];
        unsigned e4 = cbuf[s0 + 4];
        unsigned e5 = cbuf[s0 + 5];
        unsigned e6 = cbuf[s0 + 6];
        unsigned e7 = cbuf[s0 + 7];
        for (; i + 15 < c; i += 8) {
            uint2 u0 = hp2[(e0 & 0x1FFFF) * 2 + c2];
            uint2 u1 = hp2[(e1 & 0x1FFFF) * 2 + c2];
            uint2 u2 = hp2[(e2 & 0x1FFFF) * 2 + c2];
            uint2 u3 = hp2[(e3 & 0x1FFFF) * 2 + c2];
            uint2 u4 = hp2[(e4 & 0x1FFFF) * 2 + c2];
            uint2 u5 = hp2[(e5 & 0x1FFFF) * 2 + c2];
            uint2 u6 = hp2[(e6 & 0x1FFFF) * 2 + c2];
            uint2 u7 = hp2[(e7 & 0x1FFFF) * 2 + c2];
            unsigned g0 = cbuf[s0 + i + 8];
            unsigned g1 = cbuf[s0 + i + 9];
            unsigned g2 = cbuf[s0 + i + 10];
            unsigned g3 = cbuf[s0 + i + 11];
            unsigned g4 = cbuf[s0 + i + 12];
            unsigned g5 = cbuf[s0 + i + 13];
            unsigned g6 = cbuf[s0 + i + 14];
            unsigned g7 = cbuf[s0 + i + 15];
            float w0 = (float)(e0 >> 17) * QINV;
            float w1 = (float)(e1 >> 17) * QINV;
            float w2 = (float)(e2 >> 17) * QINV;
            float w3 = (float)(e3 >> 17) * QINV;
            float w4 = (float)(e4 >> 17) * QINV;
            float w5 = (float)(e5 >> 17) * QINV;
            float w6 = (float)(e6 >> 17) * QINV;
            float w7 = (float)(e7 >> 17) * QINV;
            float2 l0 = __half22float2(*(const __half2*)&u0.x);
            float2 h0 = __half22float2(*(const __half2*)&u0.y);
            float2 l1 = __half22float2(*(const __half2*)&u1.x);
            float2 h1v = __half22float2(*(const __half2*)&u1.y);
            float2 l2 = __half22float2(*(const __half2*)&u2.x);
            float2 h2v = __half22float2(*(const __half2*)&u2.y);
            float2 l3 = __half22float2(*(const __half2*)&u3.x);
            float2 h3v = __half22float2(*(const __half2*)&u3.y);
            float2 l4 = __half22float2(*(const __half2*)&u4.x);
            float2 h4v = __half22float2(*(const __half2*)&u4.y);
            float2 l5 = __half22float2(*(const __half2*)&u5.x);
            float2 h5v = __half22float2(*(const __half2*)&u5.y);
            float2 l6 = __half22float2(*(const __half2*)&u6.x);
            float2 h6v = __half22float2(*(const __half2*)&u6.y);
            float2 l7 = __half22float2(*(const __half2*)&u7.x);
            float2 h7v = __half22float2(*(const __half2*)&u7.y);
            a0 += w0 * l0.x + w1 * l1.x + w2 * l2.x + w3 * l3.x
                + w4 * l4.x + w5 * l5.x + w6 * l6.x + w7 * l7.x;
            a1 += w0 * l0.y + w1 * l1.y + w2 * l2.y + w3 * l3.y
                + w4 * l4.y + w5 * l5.y + w6 * l6.y + w7 * l7.y;
            a2 += w0 * h0.x + w1 * h1v.x + w2 * h2v.x + w3 * h3v.x
                + w4 * h4v.x + w5 * h5v.x + w6 * h6v.x + w7 * h7v.x;
            a3 += w0 * h0.y + w1 * h1v.y + w2 * h2v.y + w3 * h3v.y
                + w4 * h4v.y + w5 * h5v.y + w6 * h6v.y + w7 * h7v.y;
            e0 = g0; e1 = g1; e2 = g2; e3 = g3;
            e4 = g4; e5 = g5; e6 = g6; e7 = g7;
        }
        {
            uint2 u0 = hp2[(e0 & 0x1FFFF) * 2 + c2];
            uint2 u1 = hp2[(e1 & 0x1FFFF) * 2 + c2];
            uint2 u2 = hp2[(e2 & 0x1FFFF) * 2 + c2];
            uint2 u3 = hp2[(e3 & 0x1FFFF) * 2 + c2];
            uint2 u4 = hp2[(e4 & 0x1FFFF) * 2 + c2];
            uint2 u5 = hp2[(e5 & 0x1FFFF) * 2 + c2];
            uint2 u6 = hp2[(e6 & 0x1FFFF) * 2 + c2];
            uint2 u7 = hp2[(e7 & 0x1FFFF) * 2 + c2];
            float w0 = (float)(e0 >> 17) * QINV;
            float w1 = (float)(e1 >> 17) * QINV;
            float w2 = (float)(e2 >> 17) * QINV;
            float w3 = (float)(e3 >> 17) * QINV;
            float w4 = (float)(e4 >> 17) * QINV;
            float w5 = (float)(e5 >> 17) * QINV;
            float w6 = (float)(e6 >> 17) * QINV;
            float w7 = (float)(e7 >> 17) * QINV;
            float2 l0 = __half22float2(*(const __half2*)&u0.x);
            float2 h0 = __half22float2(*(const __half2*)&u0.y);
            float2 l1 = __half22float2(*(const __half2*)&u1.x);
            float2 h1v = __half22float2(*(const __half2*)&u1.y);
            float2 l2 = __half22float2(*(const __half2*)&u2.x);
            float2 h2v = __half22float2(*(const __half2*)&u2.y);
            float2 l3 = __half22float2(*(const __half2*)&u3.x);
            float2 h3v = __half22float2(*(const __half2*)&u3.y);
            float2 l4 = __half22float2(*(const __half2*)&u4.x);
            float2 h4v = __half22float2(*(const __half2*)&u4.y);
            float2 l5 = __half22float2(*(const __half2*)&u5.x);
            float2 h5v = __half22float2(*(const __half2*)&u5.y);
            float2 l6 = __half22float2(*(const __half2*)&u6.x);
            float2 h6v = __half22float2(*(const __half2*)&u6.y);
            float2 l7 = __half22float2(*(const __half2*)&u7.x);
            float2 h7v = __half22float2(*(const __half2*)&u7.y);
            a0 += w0 * l0.x + w1 * l1.x + w2 * l2.x + w3 * l3.x
                + w4 * l4.x + w5 * l5.x + w6 * l6.x + w7 * l7.x;
            a1 += w0 * l0.y + w1 * l1.y + w2 * l2.y + w3 * l3.y
                + w4 * l4.y + w5 * l5.y + w6 * l6.y + w7 * l7.y;
            a2 += w0 * h0.x + w1 * h1v.x + w2 * h2v.x + w3 * h3v.x
                + w4 * h4v.x + w5 * h5v.x + w6 * h6v.x + w7 * h7v.x;
            a3 += w0 * h0.y + w1 * h1v.y + w2 * h2v.y + w3 * h3v.y
                + w4 * h4v.y + w5 * h5v.y + w6 * h6v.y + w7 * h7v.y;
            i += 8;
        }
    }
    for (; i + 3 < c; i += 4) {
        unsigned e0 = cbuf[s0 + i];
        unsigned e1 = cbuf[s0 + i + 1];
        unsigned e2 = cbuf[s0 + i + 2];
        unsigned e3 = cbuf[s0 + i + 3];
        uint2 u0 = hp2[(e0 & 0x1FFFF) * 2 + c2];
        uint2 u1 = hp2[(e1 & 0x1FFFF) * 2 + c2];
        uint2 u2 = hp2[(e2 & 0x1FFFF) * 2 + c2];
        uint2 u3 = hp2[(e3 & 0x1FFFF) * 2 + c2];
        float w0 = (float)(e0 >> 17) * QINV;
        float w1 = (float)(e1 >> 17) * QINV;
        float w2 = (float)(e2 >> 17) * QINV;
        float w3 = (float)(e3 >> 17) * QINV;
        float2 l0 = __half22float2(*(const __half2*)&u0.x);
        float2 h0 = __half22float2(*(const __half2*)&u0.y);
        float2 l1 = __half22float2(*(const __half2*)&u1.x);
        float2 h1v = __half22float2(*(const __half2*)&u1.y);
        float2 l2 = __half22float2(*(const __half2*)&u2.x);
        float2 h2v = __half22float2(*(const __half2*)&u2.y);
        float2 l3 = __half22float2(*(const __half2*)&u3.x);
        float2 h3v = __half22float2(*(const __half2*)&u3.y);
        a0 += w0 * l0.x + w1 * l1.x + w2 * l2.x + w3 * l3.x;
        a1 += w0 * l0.y + w1 * l1.y + w2 * l2.y + w3 * l3.y;
        a2 += w0 * h0.x + w1 * h1v.x + w2 * h2v.x + w3 * h3v.x;
        a3 += w0 * h0.y + w1 * h1v.y + w2 * h2v.y + w3 * h3v.y;
    }
    for (; i < c; ++i) {
        unsigned e0 = cbuf[s0 + i];
        uint2 u0 = hp2[(e0 & 0x1FFFF) * 2 + c2];
        float w0 = (float)(e0 >> 17) * QINV;
        float2 l0 = __half22float2(*(const __half2*)&u0.x);
        float2 h0 = __half22float2(*(const __half2*)&u0.y);
        a0 += w0 * l0.x;
        a1 += w0 * l0.y;
        a2 += w0 * h0.x;
        a3 += w0 * h0.y;
    }
    float di = dinv[n];
    int cb = 4 * c2;
    float va0 = di * a0 + b2[cb + 0];
    float va1 = di * a1 + b2[cb + 1];
    float va2 = di * a2 + b2[cb + 2];
    float va3 = (c2 == 0) ? (di * a3 + b2[3]) : -1e30f;
    float m = fmaxf(fmaxf(va0, va1), fmaxf(va2, va3));
    m = fmaxf(m, __shfl_xor(m, 1, 2));
    float s = __expf(va0 - m) + __expf(va1 - m) + __expf(va2 - m) + __expf(va3 - m);
    s += __shfl_xor(s, 1, 2);
    float lse = m + __logf(s);
    int base = n * NC + cb;
    out[base + 0] = va0 - lse;
    out[base + 1] = va1 - lse;
    out[base + 2] = va2 - lse;
    if (c2 == 0) out[base + 3] = va3 - lse;
}

extern "C" void kernel_launch(void* const* d_in, const int* in_sizes, int n_in,
                              void* d_out, int out_size, void* d_ws, size_t ws_size,
                              hipStream_t stream) {
    const float* x  = (const float*)d_in[0];
    const int*   ei = (const int*)d_in[1];
    const float* ew = (const float*)d_in[2];
    const float* W1 = (const float*)d_in[3];
    const float* b1 = (const float*)d_in[4];
    const float* W2 = (const float*)d_in[5];
    const float* b2 = (const float*)d_in[6];
    float* out = (float*)d_out;

    const int* srcp = ei;
    const int* dstp = ei + NE;

    // ws layout (4B units)
    float*  ws   = (float*)d_ws;
    float*  dinv = ws;                          // 100352
    __half* h1p  = (__half*)(ws + 100352);      // NN*16 halves = 800000 units
    __half* h2p  = (__half*)(ws + 900352);      // NN*8 halves = 400000 units
    int*    gcur = (int*)(ws + 1300352);        // 1024
    int*    rs   = (int*)(ws + 1301376);        // 100352
    int*    rc   = (int*)(ws + 1401728);        // 100352
    uint2*  ebuf = (uint2*)(ws + 1502080);      // NB*CAP uint2 = 7,206,912 units
    const unsigned* cbuf = (const unsigned*)ebuf;  // compact u32 overlay after k_sort

    auto cdiv = [](long long a, long long b) { return (int)((a + b - 1) / b); };

    hipMemsetAsync(gcur, 0, NB * sizeof(int), stream);
    k_append<<<AB, 1024, 0, stream>>>(srcp, dstp, ew, gcur, ebuf);
    k_sort<<<NB, 1024, 0, stream>>>(gcur, ebuf, rs, rc, dinv);
    k_proj1<<<cdiv(NN, 64), 256, 0, stream>>>(x, W1, dinv, h1p);  // 1563 blocks, 4 tiles each
    k_agg1p<<<cdiv((long long)NN * 4, 256), 256, 0, stream>>>(rs, rc, cbuf, h1p, dinv, b1, W2, h2p);
    k_agg2_lsm<<<cdiv((long long)NN * 2, 256), 256, 0, stream>>>(rs, rc, cbuf, h2p, dinv, b2, out);
}